// Round 1
// baseline (2626.128 us; speedup 1.0000x reference)
//
#include <hip/hip_runtime.h>

// GraphSAGE-pool ×3 + BN + classifier, fp32.
// Inputs: 0 node_feat[N,128] f32, 1 src[E] i32, 2 dst[E] i32,
//   per layer l (base 3+5l): wp[128,128], bp[128], ws[128,128], wn[128,128], b[128]
//   18 bn_gamma[128], 19 bn_beta[128], 20 wc[128,16], 21 bc[16]
// Output: [N,16] f32.
// Workspace: 4 × N*128 f32 buffers (hp, agg, hA, hB) + 512 floats stats/coef ≈ 205 MB.

#define N_NODES 100000
#define N_EDGES 1000000
#define F 128
#define NEG_SLOPE 0.01f
#define BN_EPS 1e-5f

// ---------------- zero fill ----------------
__global__ __launch_bounds__(256) void zero_kernel(float4* __restrict__ p, long n4) {
    long i = (long)blockIdx.x * 256 + threadIdx.x;
    if (i < n4) p[i] = make_float4(0.f, 0.f, 0.f, 0.f);
}

// ---------------- fp32 GEMM: C[n,128] = act((acc?C:0) + A[n,128]@W[128,128] + bias) ----------------
// BM=64 rows/block, BN=128 (full), BK=32, 256 threads.
// act: 0=none, 1=relu, 2=leaky
__global__ __launch_bounds__(256) void gemm128(
    const float* __restrict__ A, const float* __restrict__ W,
    const float* __restrict__ bias, float* __restrict__ C,
    int n_rows, int accumulate, int act)
{
    __shared__ float As[32][68];     // [k][row], padded: 16B-aligned rows, conflict-spread
    __shared__ float Ws[32][128];    // [k][col]
    const int tid = threadIdx.x;
    const int row0 = blockIdx.x * 64;
    const int tx = tid & 15;         // cols 8*tx .. 8*tx+7
    const int ty = tid >> 4;         // rows 4*ty .. 4*ty+3

    float acc[4][8];
#pragma unroll
    for (int i = 0; i < 4; ++i)
#pragma unroll
        for (int j = 0; j < 8; ++j) acc[i][j] = 0.f;

    for (int kc = 0; kc < 4; ++kc) {
        // stage A tile (64 rows x 32 k), transposed into As[k][row]
        {
            const int r = tid >> 2, q = tid & 3;
            const int grow = row0 + r;
            const int gk = kc * 32 + q * 8;
            float4 v0 = make_float4(0.f,0.f,0.f,0.f), v1 = v0;
            if (grow < n_rows) {
                v0 = *(const float4*)(A + (size_t)grow * F + gk);
                v1 = *(const float4*)(A + (size_t)grow * F + gk + 4);
            }
            As[q*8+0][r] = v0.x; As[q*8+1][r] = v0.y; As[q*8+2][r] = v0.z; As[q*8+3][r] = v0.w;
            As[q*8+4][r] = v1.x; As[q*8+5][r] = v1.y; As[q*8+6][r] = v1.z; As[q*8+7][r] = v1.w;
        }
        // stage W tile (32 k x 128 cols), row-major (same as global)
        {
            const int wcol = (tid & 31) * 4;
            const int wr0 = tid >> 5;   // 0..7
#pragma unroll
            for (int p = 0; p < 4; ++p) {
                const int wr = wr0 + p * 8;
                *(float4*)&Ws[wr][wcol] = *(const float4*)(W + (size_t)(kc * 32 + wr) * F + wcol);
            }
        }
        __syncthreads();
#pragma unroll
        for (int k = 0; k < 32; ++k) {
            const float4 a  = *(const float4*)&As[k][ty * 4];
            const float4 w0 = *(const float4*)&Ws[k][tx * 8];
            const float4 w1 = *(const float4*)&Ws[k][tx * 8 + 4];
            const float av[4] = {a.x, a.y, a.z, a.w};
            const float wv[8] = {w0.x, w0.y, w0.z, w0.w, w1.x, w1.y, w1.z, w1.w};
#pragma unroll
            for (int i = 0; i < 4; ++i)
#pragma unroll
                for (int j = 0; j < 8; ++j)
                    acc[i][j] = fmaf(av[i], wv[j], acc[i][j]);
        }
        __syncthreads();
    }

    // epilogue
    const int c0 = tx * 8;
    float bv[8];
#pragma unroll
    for (int j = 0; j < 8; ++j) bv[j] = bias ? bias[c0 + j] : 0.f;

#pragma unroll
    for (int i = 0; i < 4; ++i) {
        const int r = row0 + ty * 4 + i;
        if (r >= n_rows) break;
        float* cp = C + (size_t)r * F + c0;
#pragma unroll
        for (int h = 0; h < 2; ++h) {
            float v[4];
#pragma unroll
            for (int j = 0; j < 4; ++j) v[j] = acc[i][h * 4 + j] + bv[h * 4 + j];
            if (accumulate) {
                const float4 o = *(const float4*)(cp + h * 4);
                v[0] += o.x; v[1] += o.y; v[2] += o.z; v[3] += o.w;
            }
            if (act == 1) {
#pragma unroll
                for (int j = 0; j < 4; ++j) v[j] = v[j] > 0.f ? v[j] : 0.f;
            } else if (act == 2) {
#pragma unroll
                for (int j = 0; j < 4; ++j) v[j] = v[j] > 0.f ? v[j] : v[j] * NEG_SLOPE;
            }
            float4 o; o.x = v[0]; o.y = v[1]; o.z = v[2]; o.w = v[3];
            *(float4*)(cp + h * 4) = o;
        }
    }
}

// ---------------- edge scatter-max ----------------
// One wave per edge (4 edges / 256-thread block); lane handles 2 feats.
// hp >= 0 (post-relu) so float max == unsigned max on bit patterns; agg init 0
// also implements the deg==0 -> 0 mask. Skip zero values (no-op vs init 0).
__global__ __launch_bounds__(256) void edge_scatter_max(
    const unsigned int* __restrict__ hp, const int* __restrict__ src,
    const int* __restrict__ dst, unsigned int* __restrict__ agg)
{
    const int e = blockIdx.x * 4 + (threadIdx.x >> 6);
    if (e >= N_EDGES) return;
    const int lane = threadIdx.x & 63;
    const int s = src[e], d = dst[e];
    const uint2 v = ((const uint2*)(hp + (size_t)s * F))[lane];
    unsigned int* dp = agg + (size_t)d * F + 2 * lane;
    if (v.x) atomicMax(dp,     v.x);
    if (v.y) atomicMax(dp + 1, v.y);
}

// ---------------- BN stats: per-column sum & sumsq ----------------
__global__ __launch_bounds__(256) void bn_stats_kernel(
    const float* __restrict__ x, float* __restrict__ stats, int n)
{
    const int tid = threadIdx.x;
    const int c = tid & 127, half = tid >> 7;
    float s = 0.f, ss = 0.f;
    const int rend = min(n, (int)(blockIdx.x + 1) * 512);
    for (int r = blockIdx.x * 512 + half; r < rend; r += 2) {
        const float v = x[(size_t)r * F + c];
        s += v; ss = fmaf(v, v, ss);
    }
    __shared__ float sh[256];
    sh[tid] = s; __syncthreads();
    if (half == 0) atomicAdd(&stats[c], sh[c] + sh[c + 128]);
    __syncthreads();
    sh[tid] = ss; __syncthreads();
    if (half == 0) atomicAdd(&stats[128 + c], sh[c] + sh[c + 128]);
}

__global__ void bn_finalize_kernel(
    const float* __restrict__ stats, const float* __restrict__ gamma,
    const float* __restrict__ beta, float* __restrict__ coef)
{
    const int c = threadIdx.x;
    const float mean = stats[c] * (1.f / N_NODES);
    const float var = stats[128 + c] * (1.f / N_NODES) - mean * mean;
    const float scale = gamma[c] * rsqrtf(var + BN_EPS);
    coef[c] = scale;
    coef[128 + c] = fmaf(-mean, scale, beta[c]);
}

__global__ __launch_bounds__(256) void bn_apply_kernel(
    float* __restrict__ x, const float* __restrict__ coef, long n4)
{
    __shared__ float sc[128], sf[128];
    if (threadIdx.x < 128) {
        sc[threadIdx.x] = coef[threadIdx.x];
        sf[threadIdx.x] = coef[128 + threadIdx.x];
    }
    __syncthreads();
    const long i = (long)blockIdx.x * 256 + threadIdx.x;
    if (i >= n4) return;
    float4 v = ((float4*)x)[i];
    const int c0 = (int)(i & 31) * 4;
    v.x = fmaf(v.x, sc[c0 + 0], sf[c0 + 0]);
    v.y = fmaf(v.y, sc[c0 + 1], sf[c0 + 1]);
    v.z = fmaf(v.z, sc[c0 + 2], sf[c0 + 2]);
    v.w = fmaf(v.w, sc[c0 + 3], sf[c0 + 3]);
    v.x = v.x > 0.f ? v.x : v.x * NEG_SLOPE;
    v.y = v.y > 0.f ? v.y : v.y * NEG_SLOPE;
    v.z = v.z > 0.f ? v.z : v.z * NEG_SLOPE;
    v.w = v.w > 0.f ? v.w : v.w * NEG_SLOPE;
    ((float4*)x)[i] = v;
}

// ---------------- classifier: out[n,16] = X[n,128]@wc[128,16] + bc ----------------
__global__ __launch_bounds__(256) void classifier_kernel(
    const float* __restrict__ X, const float* __restrict__ Wc,
    const float* __restrict__ bc, float* __restrict__ out, int n)
{
    __shared__ float Wl[2048];        // 128x16
    __shared__ float Xs[16 * 132];    // 16 rows, padded stride 132
    const int tid = threadIdx.x;
    for (int i = tid; i < 2048; i += 256) Wl[i] = Wc[i];
    const int r0 = blockIdx.x * 16;
    for (int i = tid; i < 2048; i += 256) {
        const int row = i >> 7, col = i & 127;
        const int gr = r0 + row;
        Xs[row * 132 + col] = (gr < n) ? X[(size_t)gr * F + col] : 0.f;
    }
    __syncthreads();
    const int rl = tid >> 4, c = tid & 15;
    const int r = r0 + rl;
    if (r >= n) return;
    float s = bc[c];
    const float* xr = &Xs[rl * 132];
#pragma unroll
    for (int k = 0; k < 128; ++k) s = fmaf(xr[k], Wl[k * 16 + c], s);
    out[(size_t)r * 16 + c] = s;
}

extern "C" void kernel_launch(void* const* d_in, const int* in_sizes, int n_in,
                              void* d_out, int out_size, void* d_ws, size_t ws_size,
                              hipStream_t stream) {
    const float* node_feat = (const float*)d_in[0];
    const int* src = (const int*)d_in[1];
    const int* dst = (const int*)d_in[2];
    const float* wp[3] = {(const float*)d_in[3],  (const float*)d_in[8],  (const float*)d_in[13]};
    const float* bp[3] = {(const float*)d_in[4],  (const float*)d_in[9],  (const float*)d_in[14]};
    const float* wsm[3] = {(const float*)d_in[5], (const float*)d_in[10], (const float*)d_in[15]};
    const float* wn[3] = {(const float*)d_in[6],  (const float*)d_in[11], (const float*)d_in[16]};
    const float* bb[3] = {(const float*)d_in[7],  (const float*)d_in[12], (const float*)d_in[17]};
    const float* gamma = (const float*)d_in[18];
    const float* beta  = (const float*)d_in[19];
    const float* wc    = (const float*)d_in[20];
    const float* bc    = (const float*)d_in[21];

    float* ws = (float*)d_ws;
    const size_t SZ = (size_t)N_NODES * F;          // 12.8M floats
    float* hp    = ws;
    float* agg   = ws + SZ;
    float* hA    = ws + 2 * SZ;
    float* hB    = ws + 3 * SZ;
    float* stats = ws + 4 * SZ;                     // 256 floats
    float* coef  = stats + 256;                     // 256 floats

    const int gGemm = (N_NODES + 63) / 64;          // 1563
    const long n4   = (long)(SZ / 4);               // 3.2M float4
    const int gZero = (int)((n4 + 255) / 256);      // 12500
    const int gEdge = N_EDGES / 4;                  // 250000

    const float* X = node_feat;
    float* outbuf[3] = {hA, hB, hA};
    for (int l = 0; l < 3; ++l) {
        float* Y = outbuf[l];
        zero_kernel<<<gZero, 256, 0, stream>>>((float4*)agg, n4);
        gemm128<<<gGemm, 256, 0, stream>>>(X, wp[l], bp[l], hp, N_NODES, 0, 1);   // hp = relu(X@wp+bp)
        gemm128<<<gGemm, 256, 0, stream>>>(X, wsm[l], nullptr, Y, N_NODES, 0, 0); // Y = X@ws
        edge_scatter_max<<<gEdge, 256, 0, stream>>>((const unsigned int*)hp, src, dst, (unsigned int*)agg);
        const int act = (l == 0) ? 2 : 0;
        gemm128<<<gGemm, 256, 0, stream>>>(agg, wn[l], bb[l], Y, N_NODES, 1, act); // Y = act(Y + agg@wn + b)
        if (l == 1) {
            zero_kernel<<<1, 256, 0, stream>>>((float4*)stats, 64);
            bn_stats_kernel<<<(N_NODES + 511) / 512, 256, 0, stream>>>(Y, stats, N_NODES);
            bn_finalize_kernel<<<1, 128, 0, stream>>>(stats, gamma, beta, coef);
            bn_apply_kernel<<<(int)(n4 / 256), 256, 0, stream>>>(Y, coef, n4);
        }
        X = Y;
    }
    classifier_kernel<<<(N_NODES + 15) / 16, 256, 0, stream>>>(hA, wc, bc, (float*)d_out, N_NODES);
}

// Round 2
// 1046.030 us; speedup vs baseline: 2.5106x; 2.5106x over previous
//
#include <hip/hip_runtime.h>

// GraphSAGE-pool ×3 + BN + classifier, fp32.
// R2: CSR-ized aggregation (scatter->gather). Edge atomics on 512B float rows
// (958 MB HBM write-through per phase) replaced by: build CSR once (int
// atomics, ~5 MB traffic), then per-dst-node wave gather+fmax with one clean
// row write. hp is L3-resident -> gathers served by Infinity Cache.

#define N_NODES 100000
#define N_EDGES 1000000
#define F 128
#define NEG_SLOPE 0.01f
#define BN_EPS 1e-5f

// ---------------- zero fill ----------------
__global__ __launch_bounds__(256) void zero_kernel(float4* __restrict__ p, long n4) {
    long i = (long)blockIdx.x * 256 + threadIdx.x;
    if (i < n4) p[i] = make_float4(0.f, 0.f, 0.f, 0.f);
}

// ---------------- fp32 GEMM: C[n,128] = act((acc?C:0) + A[n,128]@W[128,128] + bias) ----------------
__global__ __launch_bounds__(256) void gemm128(
    const float* __restrict__ A, const float* __restrict__ W,
    const float* __restrict__ bias, float* __restrict__ C,
    int n_rows, int accumulate, int act)
{
    __shared__ float As[32][68];
    __shared__ float Ws[32][128];
    const int tid = threadIdx.x;
    const int row0 = blockIdx.x * 64;
    const int tx = tid & 15;
    const int ty = tid >> 4;

    float acc[4][8];
#pragma unroll
    for (int i = 0; i < 4; ++i)
#pragma unroll
        for (int j = 0; j < 8; ++j) acc[i][j] = 0.f;

    for (int kc = 0; kc < 4; ++kc) {
        {
            const int r = tid >> 2, q = tid & 3;
            const int grow = row0 + r;
            const int gk = kc * 32 + q * 8;
            float4 v0 = make_float4(0.f,0.f,0.f,0.f), v1 = v0;
            if (grow < n_rows) {
                v0 = *(const float4*)(A + (size_t)grow * F + gk);
                v1 = *(const float4*)(A + (size_t)grow * F + gk + 4);
            }
            As[q*8+0][r] = v0.x; As[q*8+1][r] = v0.y; As[q*8+2][r] = v0.z; As[q*8+3][r] = v0.w;
            As[q*8+4][r] = v1.x; As[q*8+5][r] = v1.y; As[q*8+6][r] = v1.z; As[q*8+7][r] = v1.w;
        }
        {
            const int wcol = (tid & 31) * 4;
            const int wr0 = tid >> 5;
#pragma unroll
            for (int p = 0; p < 4; ++p) {
                const int wr = wr0 + p * 8;
                *(float4*)&Ws[wr][wcol] = *(const float4*)(W + (size_t)(kc * 32 + wr) * F + wcol);
            }
        }
        __syncthreads();
#pragma unroll
        for (int k = 0; k < 32; ++k) {
            const float4 a  = *(const float4*)&As[k][ty * 4];
            const float4 w0 = *(const float4*)&Ws[k][tx * 8];
            const float4 w1 = *(const float4*)&Ws[k][tx * 8 + 4];
            const float av[4] = {a.x, a.y, a.z, a.w};
            const float wv[8] = {w0.x, w0.y, w0.z, w0.w, w1.x, w1.y, w1.z, w1.w};
#pragma unroll
            for (int i = 0; i < 4; ++i)
#pragma unroll
                for (int j = 0; j < 8; ++j)
                    acc[i][j] = fmaf(av[i], wv[j], acc[i][j]);
        }
        __syncthreads();
    }

    const int c0 = tx * 8;
    float bv[8];
#pragma unroll
    for (int j = 0; j < 8; ++j) bv[j] = bias ? bias[c0 + j] : 0.f;

#pragma unroll
    for (int i = 0; i < 4; ++i) {
        const int r = row0 + ty * 4 + i;
        if (r >= n_rows) break;
        float* cp = C + (size_t)r * F + c0;
#pragma unroll
        for (int h = 0; h < 2; ++h) {
            float v[4];
#pragma unroll
            for (int j = 0; j < 4; ++j) v[j] = acc[i][h * 4 + j] + bv[h * 4 + j];
            if (accumulate) {
                const float4 o = *(const float4*)(cp + h * 4);
                v[0] += o.x; v[1] += o.y; v[2] += o.z; v[3] += o.w;
            }
            if (act == 1) {
#pragma unroll
                for (int j = 0; j < 4; ++j) v[j] = v[j] > 0.f ? v[j] : 0.f;
            } else if (act == 2) {
#pragma unroll
                for (int j = 0; j < 4; ++j) v[j] = v[j] > 0.f ? v[j] : v[j] * NEG_SLOPE;
            }
            float4 o; o.x = v[0]; o.y = v[1]; o.z = v[2]; o.w = v[3];
            *(float4*)(cp + h * 4) = o;
        }
    }
}

// ---------------- CSR build ----------------
__global__ __launch_bounds__(256) void hist_kernel(const int* __restrict__ dst, int* __restrict__ deg) {
    const int e = blockIdx.x * 256 + threadIdx.x;
    if (e < N_EDGES) atomicAdd(&deg[dst[e]], 1);
}

// per-block (1024-elem) sums
__global__ __launch_bounds__(256) void scan1_kernel(const int* __restrict__ deg, int* __restrict__ bsum) {
    __shared__ int sh[256];
    const int t = threadIdx.x;
    const int base = blockIdx.x * 1024 + t * 4;
    int s = 0;
#pragma unroll
    for (int j = 0; j < 4; ++j) s += (base + j < N_NODES) ? deg[base + j] : 0;
    sh[t] = s; __syncthreads();
    for (int off = 128; off; off >>= 1) {
        if (t < off) sh[t] += sh[t + off];
        __syncthreads();
    }
    if (t == 0) bsum[blockIdx.x] = sh[0];
}

// exclusive scan of block sums (nb <= 128), in place; also set row_start[N]
__global__ __launch_bounds__(128) void scan2_kernel(int* __restrict__ bsum, int nb, int* __restrict__ row_start) {
    __shared__ int sh[128];
    const int t = threadIdx.x;
    sh[t] = (t < nb) ? bsum[t] : 0;
    __syncthreads();
    for (int off = 1; off < 128; off <<= 1) {
        int x = (t >= off) ? sh[t - off] : 0;
        __syncthreads();
        if (t >= off) sh[t] += x;
        __syncthreads();
    }
    if (t < nb) bsum[t] = t ? sh[t - 1] : 0;
    if (t == 0) row_start[N_NODES] = N_EDGES;
}

// local exclusive scan + block offset -> row_start & cursor
__global__ __launch_bounds__(256) void scan3_kernel(
    const int* __restrict__ deg, const int* __restrict__ boff,
    int* __restrict__ row_start, int* __restrict__ cursor)
{
    __shared__ int sh[256];
    const int t = threadIdx.x;
    const int base = blockIdx.x * 1024 + t * 4;
    int v[4]; int s = 0;
#pragma unroll
    for (int j = 0; j < 4; ++j) { v[j] = (base + j < N_NODES) ? deg[base + j] : 0; s += v[j]; }
    sh[t] = s; __syncthreads();
    for (int off = 1; off < 256; off <<= 1) {
        int x = (t >= off) ? sh[t - off] : 0;
        __syncthreads();
        if (t >= off) sh[t] += x;
        __syncthreads();
    }
    int excl = (t ? sh[t - 1] : 0) + boff[blockIdx.x];
#pragma unroll
    for (int j = 0; j < 4; ++j) {
        if (base + j < N_NODES) { row_start[base + j] = excl; cursor[base + j] = excl; }
        excl += v[j];
    }
}

__global__ __launch_bounds__(256) void scatter_kernel(
    const int* __restrict__ src, const int* __restrict__ dst,
    int* __restrict__ cursor, int* __restrict__ esrc)
{
    const int e = blockIdx.x * 256 + threadIdx.x;
    if (e < N_EDGES) {
        const int pos = atomicAdd(&cursor[dst[e]], 1);
        esrc[pos] = src[e];
    }
}

// ---------------- aggregation: one wave per dst node, fmax over in-edges ----------------
// hp >= 0 (post-relu) so init-0 max == segment_max with deg==0 -> 0 mask.
__global__ __launch_bounds__(256) void aggregate_max(
    const float* __restrict__ hp, const int* __restrict__ row_start,
    const int* __restrict__ esrc, float* __restrict__ agg)
{
    const int node = blockIdx.x * 4 + (threadIdx.x >> 6);
    if (node >= N_NODES) return;
    const int lane = threadIdx.x & 63;
    const int beg = row_start[node], end = row_start[node + 1];
    float2 m = make_float2(0.f, 0.f);
    int i = beg;
    for (; i + 1 < end; i += 2) {
        const int s0 = esrc[i], s1 = esrc[i + 1];
        const float2 a = ((const float2*)(hp + (size_t)s0 * F))[lane];
        const float2 b = ((const float2*)(hp + (size_t)s1 * F))[lane];
        m.x = fmaxf(m.x, fmaxf(a.x, b.x));
        m.y = fmaxf(m.y, fmaxf(a.y, b.y));
    }
    if (i < end) {
        const float2 a = ((const float2*)(hp + (size_t)esrc[i] * F))[lane];
        m.x = fmaxf(m.x, a.x);
        m.y = fmaxf(m.y, a.y);
    }
    ((float2*)(agg + (size_t)node * F))[lane] = m;
}

// ---------------- BN ----------------
__global__ __launch_bounds__(256) void bn_stats_kernel(
    const float* __restrict__ x, float* __restrict__ stats, int n)
{
    const int tid = threadIdx.x;
    const int c = tid & 127, half = tid >> 7;
    float s = 0.f, ss = 0.f;
    const int rend = min(n, (int)(blockIdx.x + 1) * 512);
    for (int r = blockIdx.x * 512 + half; r < rend; r += 2) {
        const float v = x[(size_t)r * F + c];
        s += v; ss = fmaf(v, v, ss);
    }
    __shared__ float sh[256];
    sh[tid] = s; __syncthreads();
    if (half == 0) atomicAdd(&stats[c], sh[c] + sh[c + 128]);
    __syncthreads();
    sh[tid] = ss; __syncthreads();
    if (half == 0) atomicAdd(&stats[128 + c], sh[c] + sh[c + 128]);
}

__global__ void bn_finalize_kernel(
    const float* __restrict__ stats, const float* __restrict__ gamma,
    const float* __restrict__ beta, float* __restrict__ coef)
{
    const int c = threadIdx.x;
    const float mean = stats[c] * (1.f / N_NODES);
    const float var = stats[128 + c] * (1.f / N_NODES) - mean * mean;
    const float scale = gamma[c] * rsqrtf(var + BN_EPS);
    coef[c] = scale;
    coef[128 + c] = fmaf(-mean, scale, beta[c]);
}

__global__ __launch_bounds__(256) void bn_apply_kernel(
    float* __restrict__ x, const float* __restrict__ coef, long n4)
{
    __shared__ float sc[128], sf[128];
    if (threadIdx.x < 128) {
        sc[threadIdx.x] = coef[threadIdx.x];
        sf[threadIdx.x] = coef[128 + threadIdx.x];
    }
    __syncthreads();
    const long i = (long)blockIdx.x * 256 + threadIdx.x;
    if (i >= n4) return;
    float4 v = ((float4*)x)[i];
    const int c0 = (int)(i & 31) * 4;
    v.x = fmaf(v.x, sc[c0 + 0], sf[c0 + 0]);
    v.y = fmaf(v.y, sc[c0 + 1], sf[c0 + 1]);
    v.z = fmaf(v.z, sc[c0 + 2], sf[c0 + 2]);
    v.w = fmaf(v.w, sc[c0 + 3], sf[c0 + 3]);
    v.x = v.x > 0.f ? v.x : v.x * NEG_SLOPE;
    v.y = v.y > 0.f ? v.y : v.y * NEG_SLOPE;
    v.z = v.z > 0.f ? v.z : v.z * NEG_SLOPE;
    v.w = v.w > 0.f ? v.w : v.w * NEG_SLOPE;
    ((float4*)x)[i] = v;
}

// ---------------- classifier ----------------
__global__ __launch_bounds__(256) void classifier_kernel(
    const float* __restrict__ X, const float* __restrict__ Wc,
    const float* __restrict__ bc, float* __restrict__ out, int n)
{
    __shared__ float Wl[2048];
    __shared__ float Xs[16 * 132];
    const int tid = threadIdx.x;
    for (int i = tid; i < 2048; i += 256) Wl[i] = Wc[i];
    const int r0 = blockIdx.x * 16;
    for (int i = tid; i < 2048; i += 256) {
        const int row = i >> 7, col = i & 127;
        const int gr = r0 + row;
        Xs[row * 132 + col] = (gr < n) ? X[(size_t)gr * F + col] : 0.f;
    }
    __syncthreads();
    const int rl = tid >> 4, c = tid & 15;
    const int r = r0 + rl;
    if (r >= n) return;
    float s = bc[c];
    const float* xr = &Xs[rl * 132];
#pragma unroll
    for (int k = 0; k < 128; ++k) s = fmaf(xr[k], Wl[k * 16 + c], s);
    out[(size_t)r * 16 + c] = s;
}

extern "C" void kernel_launch(void* const* d_in, const int* in_sizes, int n_in,
                              void* d_out, int out_size, void* d_ws, size_t ws_size,
                              hipStream_t stream) {
    const float* node_feat = (const float*)d_in[0];
    const int* src = (const int*)d_in[1];
    const int* dst = (const int*)d_in[2];
    const float* wp[3] = {(const float*)d_in[3],  (const float*)d_in[8],  (const float*)d_in[13]};
    const float* bp[3] = {(const float*)d_in[4],  (const float*)d_in[9],  (const float*)d_in[14]};
    const float* wsm[3] = {(const float*)d_in[5], (const float*)d_in[10], (const float*)d_in[15]};
    const float* wn[3] = {(const float*)d_in[6],  (const float*)d_in[11], (const float*)d_in[16]};
    const float* bb[3] = {(const float*)d_in[7],  (const float*)d_in[12], (const float*)d_in[17]};
    const float* gamma = (const float*)d_in[18];
    const float* beta  = (const float*)d_in[19];
    const float* wc    = (const float*)d_in[20];
    const float* bc    = (const float*)d_in[21];

    float* ws = (float*)d_ws;
    const size_t SZ = (size_t)N_NODES * F;          // 12.8M floats
    float* B0 = ws;
    float* B1 = ws + SZ;
    float* B2 = ws + 2 * SZ;
    float* stats = ws + 3 * SZ;                     // 256 floats
    float* coef  = stats + 256;                     // 256 floats
    int* ibase = (int*)(coef + 256);
    int* deg       = ibase;                         // 100000
    int* row_start = ibase + 100000;                // 100001
    int* cursor    = ibase + 200112;                // 100000
    int* esrc      = ibase + 300112;                // 1000000
    int* bsum      = ibase + 1300112;               // 128

    const int gGemm = (N_NODES + 63) / 64;          // 1563
    const long n4   = (long)(SZ / 4);
    const int gE    = (N_EDGES + 255) / 256;        // 3907
    const int gScan = (N_NODES + 1023) / 1024;      // 98
    const int gAgg  = (N_NODES + 3) / 4;            // 25000

    // ---- build CSR (once; graph static across layers) ----
    zero_kernel<<<98, 256, 0, stream>>>((float4*)deg, 25000);   // 100000 ints
    hist_kernel<<<gE, 256, 0, stream>>>(dst, deg);
    scan1_kernel<<<gScan, 256, 0, stream>>>(deg, bsum);
    scan2_kernel<<<1, 128, 0, stream>>>(bsum, gScan, row_start);
    scan3_kernel<<<gScan, 256, 0, stream>>>(deg, bsum, row_start, cursor);
    scatter_kernel<<<gE, 256, 0, stream>>>(src, dst, cursor, esrc);

    // ---- 3 SAGE layers ----
    const float* Xl[3]   = {node_feat, B0, B1};
    float* hpbuf[3]      = {B0, B1, B2};
    float* aggbuf[3]     = {B1, B2, B0};
    for (int l = 0; l < 3; ++l) {
        const float* X = Xl[l];
        float* hp = hpbuf[l];
        float* agg = aggbuf[l];
        float* Y = hp;  // hp dead after aggregate; reuse as layer output
        gemm128<<<gGemm, 256, 0, stream>>>(X, wp[l], bp[l], hp, N_NODES, 0, 1);    // hp = relu(X@wp+bp)
        aggregate_max<<<gAgg, 256, 0, stream>>>(hp, row_start, esrc, agg);
        gemm128<<<gGemm, 256, 0, stream>>>(X, wsm[l], nullptr, Y, N_NODES, 0, 0);  // Y = X@ws
        const int act = (l == 0) ? 2 : 0;
        gemm128<<<gGemm, 256, 0, stream>>>(agg, wn[l], bb[l], Y, N_NODES, 1, act); // Y = act(Y + agg@wn + b)
        if (l == 1) {
            zero_kernel<<<1, 256, 0, stream>>>((float4*)stats, 64);
            bn_stats_kernel<<<(N_NODES + 511) / 512, 256, 0, stream>>>(Y, stats, N_NODES);
            bn_finalize_kernel<<<1, 128, 0, stream>>>(stats, gamma, beta, coef);
            bn_apply_kernel<<<(int)(n4 / 256), 256, 0, stream>>>(Y, coef, n4);
        }
    }
    classifier_kernel<<<(N_NODES + 15) / 16, 256, 0, stream>>>(B2, wc, bc, (float*)d_out, N_NODES);
}

// Round 3
// 793.988 us; speedup vs baseline: 3.3075x; 1.3174x over previous
//
#include <hip/hip_runtime.h>

// GraphSAGE-pool ×3 + BN + classifier.
// R3: bf16 activations + MFMA GEMMs (LDS-free: A-frags direct 16B coalesced
// loads, B pre-packed once into fragment order [K/8][128][8] -> contiguous,
// L1/L2-resident). Self+neigh GEMMs fused into one K=256 concat GEMM.
// Aggregation gathers bf16 rows (256B) -> half the R2 gather traffic.

#define N_NODES 100000
#define N_EDGES 1000000
#define F 128
#define NEG_SLOPE 0.01f
#define BN_EPS 1e-5f

typedef __attribute__((ext_vector_type(8))) short bf16x8;
typedef __attribute__((ext_vector_type(4))) float f32x4;

__device__ __forceinline__ unsigned short f2bf(float f) {
    unsigned int u = __float_as_uint(f);
    u += 0x7fff + ((u >> 16) & 1);          // RNE
    return (unsigned short)(u >> 16);
}
__device__ __forceinline__ float bf2f(unsigned short h) {
    return __uint_as_float(((unsigned int)h) << 16);
}

// ---------------- zero fill ----------------
__global__ __launch_bounds__(256) void zero_kernel(float4* __restrict__ p, long n4) {
    long i = (long)blockIdx.x * 256 + threadIdx.x;
    if (i < n4) p[i] = make_float4(0.f, 0.f, 0.f, 0.f);
}

// ---------------- fp32 -> bf16 convert ----------------
__global__ __launch_bounds__(256) void f32_to_bf16_kernel(
    const float4* __restrict__ in, uint2* __restrict__ out, long n4)
{
    long i = (long)blockIdx.x * 256 + threadIdx.x;
    if (i >= n4) return;
    float4 v = in[i];
    uint2 o;
    o.x = (unsigned)f2bf(v.x) | ((unsigned)f2bf(v.y) << 16);
    o.y = (unsigned)f2bf(v.z) | ((unsigned)f2bf(v.w) << 16);
    out[i] = o;
}

// ---------------- weight pack: f32 [128][128] -> bf16 frag-order [16][128][8] ----------------
// element (k,n) -> ((k>>3)*128 + n)*8 + (k&7). ws->slots 0..15, wn->slots 16..31 of wsn_p.
__global__ __launch_bounds__(256) void pack_weights3(
    const float* __restrict__ wp, const float* __restrict__ wss,
    const float* __restrict__ wn, short* __restrict__ wp_p, short* __restrict__ wsn_p)
{
    const int i = blockIdx.x * 256 + threadIdx.x;   // 0..49151
    if (i >= 3 * 16384) return;
    const int mat = i >> 14;
    const int idx = i & 16383;
    const int k = idx >> 7, n = idx & 127;
    const float* srcm = mat == 0 ? wp : (mat == 1 ? wss : wn);
    const int slot = ((k >> 3) * 128 + n) * 8 + (k & 7);
    if (mat == 0) wp_p[slot] = (short)f2bf(srcm[idx]);
    else wsn_p[(mat == 2 ? 16 * 128 * 8 : 0) + slot] = (short)f2bf(srcm[idx]);
}

// ---------------- MFMA GEMM ----------------
// C[r][c] = act( A1@B(k=0..127) [+ A2@B(k=128..255)] + bias ), all bf16 in/out, fp32 acc.
// One wave -> 64x64 output; block = 4 waves -> 128 rows x 128 cols.
// A row-major bf16 [n][128]; Bp packed [(K/8)][128][8]; no LDS.
// a-frag: A[r0+mi*16+(lane&15)][ks*32 + q*8 .. +8]  (16B contiguous)
// b-frag: Bp[ks*4+q][c0+ni*16+(lane&15)][0..8]      (16B contiguous)
// C/D: col=lane&15, row=q*4+reg (m89-verified).
template<int NKS>
__global__ __launch_bounds__(256) void gemm_mfma(
    const short* __restrict__ A1, const short* __restrict__ A2,
    const short* __restrict__ Bp, const float* __restrict__ bias,
    unsigned short* __restrict__ Cout, int n_rows, int act)
{
    const int wave = threadIdx.x >> 6;
    const int lane = threadIdx.x & 63;
    const int m = lane & 15, q = lane >> 4;
    const int r0 = blockIdx.x * 128 + (wave >> 1) * 64;
    const int c0 = (wave & 1) * 64;

    f32x4 acc[4][4];
#pragma unroll
    for (int i = 0; i < 4; ++i)
#pragma unroll
        for (int j = 0; j < 4; ++j)
#pragma unroll
            for (int r = 0; r < 4; ++r) acc[i][j][r] = 0.f;

#pragma unroll
    for (int ks = 0; ks < NKS; ++ks) {
        const short* Ap = (NKS == 8 && ks >= 4) ? A2 : A1;
        const int kk = (ks & 3) * 32 + q * 8;
        bf16x8 a[4], b[4];
#pragma unroll
        for (int mi = 0; mi < 4; ++mi) {
            const int r = r0 + mi * 16 + m;
            bf16x8 t;
#pragma unroll
            for (int j = 0; j < 8; ++j) t[j] = 0;
            if (r < n_rows) t = *(const bf16x8*)(Ap + (size_t)r * F + kk);
            a[mi] = t;
        }
#pragma unroll
        for (int ni = 0; ni < 4; ++ni)
            b[ni] = *(const bf16x8*)(Bp + ((size_t)(ks * 4 + q) * F + c0 + ni * 16 + m) * 8);
#pragma unroll
        for (int mi = 0; mi < 4; ++mi)
#pragma unroll
            for (int ni = 0; ni < 4; ++ni)
                acc[mi][ni] = __builtin_amdgcn_mfma_f32_16x16x32_bf16(a[mi], b[ni], acc[mi][ni], 0, 0, 0);
    }

    float bv[4];
#pragma unroll
    for (int ni = 0; ni < 4; ++ni) bv[ni] = bias[c0 + ni * 16 + m];

#pragma unroll
    for (int mi = 0; mi < 4; ++mi)
#pragma unroll
        for (int ni = 0; ni < 4; ++ni) {
            const int c = c0 + ni * 16 + m;
#pragma unroll
            for (int rg = 0; rg < 4; ++rg) {
                const int r = r0 + mi * 16 + q * 4 + rg;
                if (r < n_rows) {
                    float v = acc[mi][ni][rg] + bv[ni];
                    if (act == 1) v = v > 0.f ? v : 0.f;
                    else if (act == 2) v = v > 0.f ? v : v * NEG_SLOPE;
                    Cout[(size_t)r * F + c] = f2bf(v);
                }
            }
        }
}

// ---------------- CSR build ----------------
__global__ __launch_bounds__(256) void hist_kernel(const int* __restrict__ dst, int* __restrict__ deg) {
    const int e = blockIdx.x * 256 + threadIdx.x;
    if (e < N_EDGES) atomicAdd(&deg[dst[e]], 1);
}

__global__ __launch_bounds__(256) void scan1_kernel(const int* __restrict__ deg, int* __restrict__ bsum) {
    __shared__ int sh[256];
    const int t = threadIdx.x;
    const int base = blockIdx.x * 1024 + t * 4;
    int s = 0;
#pragma unroll
    for (int j = 0; j < 4; ++j) s += (base + j < N_NODES) ? deg[base + j] : 0;
    sh[t] = s; __syncthreads();
    for (int off = 128; off; off >>= 1) {
        if (t < off) sh[t] += sh[t + off];
        __syncthreads();
    }
    if (t == 0) bsum[blockIdx.x] = sh[0];
}

__global__ __launch_bounds__(128) void scan2_kernel(int* __restrict__ bsum, int nb, int* __restrict__ row_start) {
    __shared__ int sh[128];
    const int t = threadIdx.x;
    sh[t] = (t < nb) ? bsum[t] : 0;
    __syncthreads();
    for (int off = 1; off < 128; off <<= 1) {
        int x = (t >= off) ? sh[t - off] : 0;
        __syncthreads();
        if (t >= off) sh[t] += x;
        __syncthreads();
    }
    if (t < nb) bsum[t] = t ? sh[t - 1] : 0;
    if (t == 0) row_start[N_NODES] = N_EDGES;
}

__global__ __launch_bounds__(256) void scan3_kernel(
    const int* __restrict__ deg, const int* __restrict__ boff,
    int* __restrict__ row_start, int* __restrict__ cursor)
{
    __shared__ int sh[256];
    const int t = threadIdx.x;
    const int base = blockIdx.x * 1024 + t * 4;
    int v[4]; int s = 0;
#pragma unroll
    for (int j = 0; j < 4; ++j) { v[j] = (base + j < N_NODES) ? deg[base + j] : 0; s += v[j]; }
    sh[t] = s; __syncthreads();
    for (int off = 1; off < 256; off <<= 1) {
        int x = (t >= off) ? sh[t - off] : 0;
        __syncthreads();
        if (t >= off) sh[t] += x;
        __syncthreads();
    }
    int excl = (t ? sh[t - 1] : 0) + boff[blockIdx.x];
#pragma unroll
    for (int j = 0; j < 4; ++j) {
        if (base + j < N_NODES) { row_start[base + j] = excl; cursor[base + j] = excl; }
        excl += v[j];
    }
}

__global__ __launch_bounds__(256) void scatter_kernel(
    const int* __restrict__ src, const int* __restrict__ dst,
    int* __restrict__ cursor, int* __restrict__ esrc)
{
    const int e = blockIdx.x * 256 + threadIdx.x;
    if (e < N_EDGES) {
        const int pos = atomicAdd(&cursor[dst[e]], 1);
        esrc[pos] = src[e];
    }
}

// ---------------- aggregation: one wave per dst node, bf16 rows ----------------
// hp >= 0 post-relu: bf16 bit pattern order == numeric order; init 0 == deg-mask.
__global__ __launch_bounds__(256) void aggregate_max_bf16(
    const unsigned int* __restrict__ hp, const int* __restrict__ row_start,
    const int* __restrict__ esrc, unsigned int* __restrict__ agg)
{
    const int node = blockIdx.x * 4 + (threadIdx.x >> 6);
    if (node >= N_NODES) return;
    const int lane = threadIdx.x & 63;
    const int beg = row_start[node], end = row_start[node + 1];
    unsigned int m0 = 0, m1 = 0;     // two ushort maxes
    int i = beg;
    for (; i + 1 < end; i += 2) {
        const unsigned int a = hp[(size_t)esrc[i] * 64 + lane];
        const unsigned int b = hp[(size_t)esrc[i + 1] * 64 + lane];
        const unsigned int ax = a & 0xffffu, ay = a >> 16;
        const unsigned int bx = b & 0xffffu, by = b >> 16;
        m0 = max(m0, max(ax, bx));
        m1 = max(m1, max(ay, by));
    }
    if (i < end) {
        const unsigned int a = hp[(size_t)esrc[i] * 64 + lane];
        m0 = max(m0, a & 0xffffu);
        m1 = max(m1, a >> 16);
    }
    agg[(size_t)node * 64 + lane] = m0 | (m1 << 16);
}

// ---------------- BN ----------------
__global__ __launch_bounds__(256) void bn_stats_kernel(
    const unsigned short* __restrict__ x, float* __restrict__ stats, int n)
{
    const int tid = threadIdx.x;
    const int c = tid & 127, half = tid >> 7;
    float s = 0.f, ss = 0.f;
    const int rend = min(n, (int)(blockIdx.x + 1) * 512);
    for (int r = blockIdx.x * 512 + half; r < rend; r += 2) {
        const float v = bf2f(x[(size_t)r * F + c]);
        s += v; ss = fmaf(v, v, ss);
    }
    __shared__ float sh[256];
    sh[tid] = s; __syncthreads();
    if (half == 0) atomicAdd(&stats[c], sh[c] + sh[c + 128]);
    __syncthreads();
    sh[tid] = ss; __syncthreads();
    if (half == 0) atomicAdd(&stats[128 + c], sh[c] + sh[c + 128]);
}

__global__ void bn_finalize_kernel(
    const float* __restrict__ stats, const float* __restrict__ gamma,
    const float* __restrict__ beta, float* __restrict__ coef)
{
    const int c = threadIdx.x;
    const float mean = stats[c] * (1.f / N_NODES);
    const float var = stats[128 + c] * (1.f / N_NODES) - mean * mean;
    const float scale = gamma[c] * rsqrtf(var + BN_EPS);
    coef[c] = scale;
    coef[128 + c] = fmaf(-mean, scale, beta[c]);
}

__global__ __launch_bounds__(256) void bn_apply_bf16(
    unsigned int* __restrict__ x, const float* __restrict__ coef, long n2)
{
    __shared__ float sc[128], sf[128];
    if (threadIdx.x < 128) {
        sc[threadIdx.x] = coef[threadIdx.x];
        sf[threadIdx.x] = coef[128 + threadIdx.x];
    }
    __syncthreads();
    const long i = (long)blockIdx.x * 256 + threadIdx.x;
    if (i >= n2) return;
    const unsigned int v = x[i];
    const int c0 = (int)(i & 63) * 2;
    float a = fmaf(bf2f((unsigned short)(v & 0xffffu)), sc[c0], sf[c0]);
    float b = fmaf(bf2f((unsigned short)(v >> 16)), sc[c0 + 1], sf[c0 + 1]);
    a = a > 0.f ? a : a * NEG_SLOPE;
    b = b > 0.f ? b : b * NEG_SLOPE;
    x[i] = (unsigned)f2bf(a) | ((unsigned)f2bf(b) << 16);
}

// ---------------- classifier: out[n,16] = X[n,128]@wc[128,16] + bc (fp32 math) ----------------
__global__ __launch_bounds__(256) void classifier_kernel(
    const unsigned short* __restrict__ X, const float* __restrict__ Wc,
    const float* __restrict__ bc, float* __restrict__ out, int n)
{
    __shared__ float Wl[2048];
    __shared__ float Xs[16 * 132];
    const int tid = threadIdx.x;
    for (int i = tid; i < 2048; i += 256) Wl[i] = Wc[i];
    const int r0 = blockIdx.x * 16;
    for (int i = tid; i < 2048; i += 256) {
        const int row = i >> 7, col = i & 127;
        const int gr = r0 + row;
        Xs[row * 132 + col] = (gr < n) ? bf2f(X[(size_t)gr * F + col]) : 0.f;
    }
    __syncthreads();
    const int rl = tid >> 4, c = tid & 15;
    const int r = r0 + rl;
    if (r >= n) return;
    float s = bc[c];
    const float* xr = &Xs[rl * 132];
#pragma unroll
    for (int k = 0; k < 128; ++k) s = fmaf(xr[k], Wl[k * 16 + c], s);
    out[(size_t)r * 16 + c] = s;
}

extern "C" void kernel_launch(void* const* d_in, const int* in_sizes, int n_in,
                              void* d_out, int out_size, void* d_ws, size_t ws_size,
                              hipStream_t stream) {
    const float* node_feat = (const float*)d_in[0];
    const int* src = (const int*)d_in[1];
    const int* dst = (const int*)d_in[2];
    const float* wp[3] = {(const float*)d_in[3],  (const float*)d_in[8],  (const float*)d_in[13]};
    const float* bp[3] = {(const float*)d_in[4],  (const float*)d_in[9],  (const float*)d_in[14]};
    const float* wsm[3] = {(const float*)d_in[5], (const float*)d_in[10], (const float*)d_in[15]};
    const float* wn[3] = {(const float*)d_in[6],  (const float*)d_in[11], (const float*)d_in[16]};
    const float* bb[3] = {(const float*)d_in[7],  (const float*)d_in[12], (const float*)d_in[17]};
    const float* gamma = (const float*)d_in[18];
    const float* beta  = (const float*)d_in[19];
    const float* wc    = (const float*)d_in[20];
    const float* bc    = (const float*)d_in[21];

    const size_t SZ = (size_t)N_NODES * F;          // 12.8M elements
    short* sbase = (short*)d_ws;
    short* B0  = sbase;
    short* B1  = sbase + SZ;
    short* B2  = sbase + 2 * SZ;
    short* Xbf = sbase + 3 * SZ;
    short* wp_p  = sbase + 4 * SZ;                  // 3 × 16384
    short* wsn_p = wp_p + 3 * 16384;                // 3 × 32768
    float* fbase = (float*)(wsn_p + 3 * 32768);     // 16B-aligned
    float* stats = fbase;                           // 256
    float* coef  = fbase + 256;                     // 256
    int* ibase = (int*)(fbase + 512);
    int* deg       = ibase;                         // 100000
    int* row_start = ibase + 100000;                // 100001
    int* cursor    = ibase + 200104;                // 100000
    int* esrc      = ibase + 300104;                // 1000000
    int* bsum      = ibase + 1300104;               // 128

    const int gGemm = (N_NODES + 127) / 128;        // 782
    const int gE    = (N_EDGES + 255) / 256;        // 3907
    const int gScan = (N_NODES + 1023) / 1024;      // 98
    const int gAgg  = (N_NODES + 3) / 4;            // 25000
    const long cvt4 = (long)(SZ / 4);               // 3.2M
    const long n2   = (long)(SZ / 2);               // 6.4M

    // ---- prep: bf16 node features + packed bf16 weights ----
    f32_to_bf16_kernel<<<(int)((cvt4 + 255) / 256), 256, 0, stream>>>(
        (const float4*)node_feat, (uint2*)Xbf, cvt4);
    for (int l = 0; l < 3; ++l)
        pack_weights3<<<192, 256, 0, stream>>>(wp[l], wsm[l], wn[l],
                                               wp_p + l * 16384, wsn_p + l * 32768);

    // ---- build CSR (graph static across layers) ----
    zero_kernel<<<98, 256, 0, stream>>>((float4*)deg, 25000);
    hist_kernel<<<gE, 256, 0, stream>>>(dst, deg);
    scan1_kernel<<<gScan, 256, 0, stream>>>(deg, bsum);
    scan2_kernel<<<1, 128, 0, stream>>>(bsum, gScan, row_start);
    scan3_kernel<<<gScan, 256, 0, stream>>>(deg, bsum, row_start, cursor);
    scatter_kernel<<<gE, 256, 0, stream>>>(src, dst, cursor, esrc);

    // ---- 3 SAGE layers ----
    const short* Xl[3]  = {Xbf, B0, B1};
    short* hpb[3]       = {B0, B1, B0};
    short* aggb[3]      = {B1, B2, B2};
    short* Yb[3]        = {B0, B1, B0};
    for (int l = 0; l < 3; ++l) {
        const short* X = Xl[l];
        // hp = relu(X@wp + bp)
        gemm_mfma<4><<<gGemm, 256, 0, stream>>>(X, (const short*)nullptr,
            wp_p + l * 16384, bp[l], (unsigned short*)hpb[l], N_NODES, 1);
        aggregate_max_bf16<<<gAgg, 256, 0, stream>>>(
            (const unsigned int*)hpb[l], row_start, esrc, (unsigned int*)aggb[l]);
        // Y = act(X@ws + agg@wn + b), K=256 concat
        const int act = (l == 0) ? 2 : 0;
        gemm_mfma<8><<<gGemm, 256, 0, stream>>>(X, aggb[l],
            wsn_p + l * 32768, bb[l], (unsigned short*)Yb[l], N_NODES, act);
        if (l == 1) {
            zero_kernel<<<1, 256, 0, stream>>>((float4*)stats, 64);
            bn_stats_kernel<<<(N_NODES + 511) / 512, 256, 0, stream>>>(
                (const unsigned short*)Yb[l], stats, N_NODES);
            bn_finalize_kernel<<<1, 128, 0, stream>>>(stats, gamma, beta, coef);
            bn_apply_bf16<<<(int)((n2 + 255) / 256), 256, 0, stream>>>(
                (unsigned int*)Yb[l], coef, n2);
        }
    }
    classifier_kernel<<<(N_NODES + 15) / 16, 256, 0, stream>>>(
        (const unsigned short*)B0, wc, bc, (float*)d_out, N_NODES);
}

// Round 5
// 654.376 us; speedup vs baseline: 4.0132x; 1.2134x over previous
//
#include <hip/hip_runtime.h>

// GraphSAGE-pool ×3 + BN + classifier, bf16 activations + MFMA GEMMs.
// R5 = R4 + two fixes:
//  (1) a-frag ds_read was missing the wave row-quadrant offset (wave>>1)*64
//      -> waves 2/3 computed rows 0..63's results (R4 absmax 1.57). Fixed.
//  (2) epilogue LDS bounce: intra-wave cross-lane write->read now bracketed
//      by __syncthreads() (don't rely on alias analysis for lgkmcnt).

#define N_NODES 100000
#define N_EDGES 1000000
#define F 128
#define NEG_SLOPE 0.01f
#define BN_EPS 1e-5f

typedef __attribute__((ext_vector_type(8))) short bf16x8;
typedef __attribute__((ext_vector_type(4))) float f32x4;

typedef __attribute__((address_space(3))) unsigned int as3_uint;
typedef __attribute__((address_space(1))) const unsigned int as1_cuint;

__device__ __forceinline__ void gload16(const void* g, void* l) {
    __builtin_amdgcn_global_load_lds((as1_cuint*)g, (as3_uint*)l, 16, 0, 0);
}

__device__ __forceinline__ unsigned short f2bf(float f) {
    unsigned int u = __float_as_uint(f);
    u += 0x7fff + ((u >> 16) & 1);          // RNE
    return (unsigned short)(u >> 16);
}
__device__ __forceinline__ float bf2f(unsigned short h) {
    return __uint_as_float(((unsigned int)h) << 16);
}

// ---------------- zero fill ----------------
__global__ __launch_bounds__(256) void zero_kernel(float4* __restrict__ p, long n4) {
    long i = (long)blockIdx.x * 256 + threadIdx.x;
    if (i < n4) p[i] = make_float4(0.f, 0.f, 0.f, 0.f);
}

// ---------------- fp32 -> bf16 convert ----------------
__global__ __launch_bounds__(256) void f32_to_bf16_kernel(
    const float4* __restrict__ in, uint2* __restrict__ out, long n4)
{
    long i = (long)blockIdx.x * 256 + threadIdx.x;
    if (i >= n4) return;
    float4 v = in[i];
    uint2 o;
    o.x = (unsigned)f2bf(v.x) | ((unsigned)f2bf(v.y) << 16);
    o.y = (unsigned)f2bf(v.z) | ((unsigned)f2bf(v.w) << 16);
    out[i] = o;
}

// ---------------- weight pack: f32 [128][128] -> bf16 frag-order [16][128][8] ----------------
// element (k,n) -> ((k>>3)*128 + n)*8 + (k&7). ws->slots 0..15, wn->slots 16..31 of wsn_p.
__global__ __launch_bounds__(256) void pack_weights3(
    const float* __restrict__ wp, const float* __restrict__ wss,
    const float* __restrict__ wn, short* __restrict__ wp_p, short* __restrict__ wsn_p)
{
    const int i = blockIdx.x * 256 + threadIdx.x;   // 0..49151
    if (i >= 3 * 16384) return;
    const int mat = i >> 14;
    const int idx = i & 16383;
    const int k = idx >> 7, n = idx & 127;
    const float* srcm = mat == 0 ? wp : (mat == 1 ? wss : wn);
    const int slot = ((k >> 3) * 128 + n) * 8 + (k & 7);
    if (mat == 0) wp_p[slot] = (short)f2bf(srcm[idx]);
    else wsn_p[(mat == 2 ? 16 * 128 * 8 : 0) + slot] = (short)f2bf(srcm[idx]);
}

// ---------------- MFMA GEMM, m97-style ----------------
// C = act(A1@B[k 0..127] [+ A2@B[k 128..255]] + bias); bf16 in/out, fp32 acc.
// Block: 256 thr = 4 waves, tile 128x128. Wave -> 64x64 quadrant.
// A staged in LDS (BK=64, double buffer) via global_load_lds w/ XOR chunk
// swizzle: LDS slot s of row r holds global 16B-chunk s^(r&7); reader of
// logical chunk c at row r uses slot c^(r&7) -> bank-balanced ds_read_b128.
// B direct from packed Bp [(K/8)][128][8] (32-64 KB, L2-resident).
// Epilogue: per-wave LDS bounce -> bf16x8 coalesced stores.
template<int NKS>
__global__ __launch_bounds__(256) void gemm_mfma(
    const short* __restrict__ A1, const short* __restrict__ A2,
    const short* __restrict__ Bp, const float* __restrict__ bias,
    unsigned short* __restrict__ Cout, int n_rows, int act)
{
    constexpr int S = NKS / 2;                   // BK=64 steps
    __shared__ short tile[2 * 8192];             // 2 x (128 rows x 64 cols)
    __shared__ short epi[4 * 1280];              // per-wave 16 x 80

    const int tid = threadIdx.x;
    const int wave = tid >> 6;
    const int lane = tid & 63;
    const int m = lane & 15, q = lane >> 4;
    const int r0 = blockIdx.x * 128;
    const int rw = (wave >> 1) * 64;             // wave row-quadrant offset
    const int r0q = r0 + rw;
    const int c0 = (wave & 1) * 64;
    const int gchunk = (tid & 7) ^ ((tid >> 3) & 7);

    f32x4 acc[4][4];
#pragma unroll
    for (int i = 0; i < 4; ++i)
#pragma unroll
        for (int j = 0; j < 4; ++j)
#pragma unroll
            for (int r = 0; r < 4; ++r) acc[i][j][r] = 0.f;

    auto stage = [&](int s, int buf) {
        const short* Ap = (NKS == 8 && s >= 2) ? A2 : A1;
        const int kbase = (s & 1) * 64;          // shorts
#pragma unroll
        for (int p = 0; p < 4; ++p) {
            int row = r0 + (tid >> 3) + 32 * p;
            row = min(row, n_rows - 1);
            gload16(Ap + (size_t)row * F + kbase + gchunk * 8,
                    &tile[buf * 8192 + p * 2048 + tid * 8]);
        }
    };

    stage(0, 0);
    __syncthreads();

    for (int s = 0; s < S; ++s) {
        if (s + 1 < S) stage(s + 1, (s + 1) & 1);
        const short* tb = &tile[(s & 1) * 8192];
#pragma unroll
        for (int ks2 = 0; ks2 < 2; ++ks2) {
            const int ks32 = s * 2 + ks2;
            bf16x8 b[4], a[4];
#pragma unroll
            for (int ni = 0; ni < 4; ++ni)
                b[ni] = *(const bf16x8*)(Bp + ((size_t)(ks32 * 4 + q) * F + c0 + ni * 16 + m) * 8);
#pragma unroll
            for (int mi = 0; mi < 4; ++mi)
                a[mi] = *(const bf16x8*)(tb + (rw + mi * 16 + m) * 64 + (((ks2 * 4 + q) ^ (m & 7)) << 3));
#pragma unroll
            for (int mi = 0; mi < 4; ++mi)
#pragma unroll
                for (int ni = 0; ni < 4; ++ni)
                    acc[mi][ni] = __builtin_amdgcn_mfma_f32_16x16x32_bf16(a[mi], b[ni], acc[mi][ni], 0, 0, 0);
        }
        __syncthreads();
    }

    float bv[4];
#pragma unroll
    for (int ni = 0; ni < 4; ++ni) bv[ni] = bias[c0 + ni * 16 + m];

    short* ep = &epi[wave * 1280];
    const int colc_lo = m >> 3, cin = m & 7;
#pragma unroll
    for (int mi = 0; mi < 4; ++mi) {
        // write this 16-row slab into per-wave LDS (swizzled chunks, stride 80)
#pragma unroll
        for (int ni = 0; ni < 4; ++ni) {
            const int colc = 2 * ni + colc_lo;
#pragma unroll
            for (int rg = 0; rg < 4; ++rg) {
                const int row16 = q * 4 + rg;
                float v = acc[mi][ni][rg] + bv[ni];
                if (act == 1) v = v > 0.f ? v : 0.f;
                else if (act == 2) v = v > 0.f ? v : v * NEG_SLOPE;
                ep[row16 * 80 + ((colc ^ (row16 & 7)) << 3) + cin] = (short)f2bf(v);
            }
        }
        __syncthreads();   // intra-wave cross-lane LDS RAW; uniform across waves
        // read back coalesced and store 16B/lane
#pragma unroll
        for (int p = 0; p < 2; ++p) {
            const int lrow = (lane >> 3) + 8 * p;
            bf16x8 vv = *(const bf16x8*)&ep[lrow * 80 + (((lane & 7) ^ (lrow & 7)) << 3)];
            const int grow = r0q + mi * 16 + lrow;
            if (grow < n_rows)
                *(bf16x8*)(Cout + (size_t)grow * F + c0 + ((lane & 7) << 3)) = vv;
        }
        __syncthreads();   // protect buffer before next slab's writes
    }
}

// ---------------- CSR build ----------------
__global__ __launch_bounds__(256) void hist_kernel(const int* __restrict__ dst, int* __restrict__ deg) {
    const int e = blockIdx.x * 256 + threadIdx.x;
    if (e < N_EDGES) atomicAdd(&deg[dst[e]], 1);
}

__global__ __launch_bounds__(256) void scan1_kernel(const int* __restrict__ deg, int* __restrict__ bsum) {
    __shared__ int sh[256];
    const int t = threadIdx.x;
    const int base = blockIdx.x * 1024 + t * 4;
    int s = 0;
#pragma unroll
    for (int j = 0; j < 4; ++j) s += (base + j < N_NODES) ? deg[base + j] : 0;
    sh[t] = s; __syncthreads();
    for (int off = 128; off; off >>= 1) {
        if (t < off) sh[t] += sh[t + off];
        __syncthreads();
    }
    if (t == 0) bsum[blockIdx.x] = sh[0];
}

__global__ __launch_bounds__(128) void scan2_kernel(int* __restrict__ bsum, int nb, int* __restrict__ row_start) {
    __shared__ int sh[128];
    const int t = threadIdx.x;
    sh[t] = (t < nb) ? bsum[t] : 0;
    __syncthreads();
    for (int off = 1; off < 128; off <<= 1) {
        int x = (t >= off) ? sh[t - off] : 0;
        __syncthreads();
        if (t >= off) sh[t] += x;
        __syncthreads();
    }
    if (t < nb) bsum[t] = t ? sh[t - 1] : 0;
    if (t == 0) row_start[N_NODES] = N_EDGES;
}

__global__ __launch_bounds__(256) void scan3_kernel(
    const int* __restrict__ deg, const int* __restrict__ boff,
    int* __restrict__ row_start, int* __restrict__ cursor)
{
    __shared__ int sh[256];
    const int t = threadIdx.x;
    const int base = blockIdx.x * 1024 + t * 4;
    int v[4]; int s = 0;
#pragma unroll
    for (int j = 0; j < 4; ++j) { v[j] = (base + j < N_NODES) ? deg[base + j] : 0; s += v[j]; }
    sh[t] = s; __syncthreads();
    for (int off = 1; off < 256; off <<= 1) {
        int x = (t >= off) ? sh[t - off] : 0;
        __syncthreads();
        if (t >= off) sh[t] += x;
        __syncthreads();
    }
    int excl = (t ? sh[t - 1] : 0) + boff[blockIdx.x];
#pragma unroll
    for (int j = 0; j < 4; ++j) {
        if (base + j < N_NODES) { row_start[base + j] = excl; cursor[base + j] = excl; }
        excl += v[j];
    }
}

__global__ __launch_bounds__(256) void scatter_kernel(
    const int* __restrict__ src, const int* __restrict__ dst,
    int* __restrict__ cursor, int* __restrict__ esrc)
{
    const int e = blockIdx.x * 256 + threadIdx.x;
    if (e < N_EDGES) {
        const int pos = atomicAdd(&cursor[dst[e]], 1);
        esrc[pos] = src[e];
    }
}

// ---------------- aggregation: one wave per dst node, bf16 rows, 4-deep MLP ----------------
__global__ __launch_bounds__(256) void aggregate_max_bf16(
    const unsigned int* __restrict__ hp, const int* __restrict__ row_start,
    const int* __restrict__ esrc, unsigned int* __restrict__ agg)
{
    const int node = blockIdx.x * 4 + (threadIdx.x >> 6);
    if (node >= N_NODES) return;
    const int lane = threadIdx.x & 63;
    const int beg = row_start[node], end = row_start[node + 1];
    unsigned int m0 = 0, m1 = 0;
    int i = beg;
    for (; i + 3 < end; i += 4) {
        const int s0 = esrc[i], s1 = esrc[i + 1], s2 = esrc[i + 2], s3 = esrc[i + 3];
        const unsigned int a = hp[(size_t)s0 * 64 + lane];
        const unsigned int b = hp[(size_t)s1 * 64 + lane];
        const unsigned int c = hp[(size_t)s2 * 64 + lane];
        const unsigned int d = hp[(size_t)s3 * 64 + lane];
        const unsigned int ab0 = max(a & 0xffffu, b & 0xffffu);
        const unsigned int cd0 = max(c & 0xffffu, d & 0xffffu);
        const unsigned int ab1 = max(a >> 16, b >> 16);
        const unsigned int cd1 = max(c >> 16, d >> 16);
        m0 = max(m0, max(ab0, cd0));
        m1 = max(m1, max(ab1, cd1));
    }
    if (i + 1 < end) {
        const unsigned int a = hp[(size_t)esrc[i] * 64 + lane];
        const unsigned int b = hp[(size_t)esrc[i + 1] * 64 + lane];
        m0 = max(m0, max(a & 0xffffu, b & 0xffffu));
        m1 = max(m1, max(a >> 16, b >> 16));
        i += 2;
    }
    if (i < end) {
        const unsigned int a = hp[(size_t)esrc[i] * 64 + lane];
        m0 = max(m0, a & 0xffffu);
        m1 = max(m1, a >> 16);
    }
    agg[(size_t)node * 64 + lane] = m0 | (m1 << 16);
}

// ---------------- BN ----------------
__global__ __launch_bounds__(256) void bn_stats_kernel(
    const unsigned short* __restrict__ x, float* __restrict__ stats, int n)
{
    const int tid = threadIdx.x;
    const int c = tid & 127, half = tid >> 7;
    float s = 0.f, ss = 0.f;
    const int rend = min(n, (int)(blockIdx.x + 1) * 512);
    for (int r = blockIdx.x * 512 + half; r < rend; r += 2) {
        const float v = bf2f(x[(size_t)r * F + c]);
        s += v; ss = fmaf(v, v, ss);
    }
    __shared__ float sh[256];
    sh[tid] = s; __syncthreads();
    if (half == 0) atomicAdd(&stats[c], sh[c] + sh[c + 128]);
    __syncthreads();
    sh[tid] = ss; __syncthreads();
    if (half == 0) atomicAdd(&stats[128 + c], sh[c] + sh[c + 128]);
}

__global__ void bn_finalize_kernel(
    const float* __restrict__ stats, const float* __restrict__ gamma,
    const float* __restrict__ beta, float* __restrict__ coef)
{
    const int c = threadIdx.x;
    const float mean = stats[c] * (1.f / N_NODES);
    const float var = stats[128 + c] * (1.f / N_NODES) - mean * mean;
    const float scale = gamma[c] * rsqrtf(var + BN_EPS);
    coef[c] = scale;
    coef[128 + c] = fmaf(-mean, scale, beta[c]);
}

__global__ __launch_bounds__(256) void bn_apply_bf16(
    unsigned int* __restrict__ x, const float* __restrict__ coef, long n2)
{
    __shared__ float sc[128], sf[128];
    if (threadIdx.x < 128) {
        sc[threadIdx.x] = coef[threadIdx.x];
        sf[threadIdx.x] = coef[128 + threadIdx.x];
    }
    __syncthreads();
    const long i = (long)blockIdx.x * 256 + threadIdx.x;
    if (i >= n2) return;
    const unsigned int v = x[i];
    const int c0 = (int)(i & 63) * 2;
    float a = fmaf(bf2f((unsigned short)(v & 0xffffu)), sc[c0], sf[c0]);
    float b = fmaf(bf2f((unsigned short)(v >> 16)), sc[c0 + 1], sf[c0 + 1]);
    a = a > 0.f ? a : a * NEG_SLOPE;
    b = b > 0.f ? b : b * NEG_SLOPE;
    x[i] = (unsigned)f2bf(a) | ((unsigned)f2bf(b) << 16);
}

// ---------------- classifier ----------------
__global__ __launch_bounds__(256) void classifier_kernel(
    const unsigned short* __restrict__ X, const float* __restrict__ Wc,
    const float* __restrict__ bc, float* __restrict__ out, int n)
{
    __shared__ float Wl[2048];
    __shared__ float Xs[16 * 132];
    const int tid = threadIdx.x;
    for (int i = tid; i < 2048; i += 256) Wl[i] = Wc[i];
    const int r0 = blockIdx.x * 16;
    for (int i = tid; i < 2048; i += 256) {
        const int row = i >> 7, col = i & 127;
        const int gr = r0 + row;
        Xs[row * 132 + col] = (gr < n) ? bf2f(X[(size_t)gr * F + col]) : 0.f;
    }
    __syncthreads();
    const int rl = tid >> 4, c = tid & 15;
    const int r = r0 + rl;
    if (r >= n) return;
    float s = bc[c];
    const float* xr = &Xs[rl * 132];
#pragma unroll
    for (int k = 0; k < 128; ++k) s = fmaf(xr[k], Wl[k * 16 + c], s);
    out[(size_t)r * 16 + c] = s;
}

extern "C" void kernel_launch(void* const* d_in, const int* in_sizes, int n_in,
                              void* d_out, int out_size, void* d_ws, size_t ws_size,
                              hipStream_t stream) {
    const float* node_feat = (const float*)d_in[0];
    const int* src = (const int*)d_in[1];
    const int* dst = (const int*)d_in[2];
    const float* wp[3] = {(const float*)d_in[3],  (const float*)d_in[8],  (const float*)d_in[13]};
    const float* bp[3] = {(const float*)d_in[4],  (const float*)d_in[9],  (const float*)d_in[14]};
    const float* wsm[3] = {(const float*)d_in[5], (const float*)d_in[10], (const float*)d_in[15]};
    const float* wn[3] = {(const float*)d_in[6],  (const float*)d_in[11], (const float*)d_in[16]};
    const float* bb[3] = {(const float*)d_in[7],  (const float*)d_in[12], (const float*)d_in[17]};
    const float* gamma = (const float*)d_in[18];
    const float* beta  = (const float*)d_in[19];
    const float* wc    = (const float*)d_in[20];
    const float* bc    = (const float*)d_in[21];

    const size_t SZ = (size_t)N_NODES * F;          // 12.8M elements
    short* sbase = (short*)d_ws;
    short* B0  = sbase;
    short* B1  = sbase + SZ;
    short* B2  = sbase + 2 * SZ;
    short* Xbf = sbase + 3 * SZ;
    short* wp_p  = sbase + 4 * SZ;                  // 3 × 16384
    short* wsn_p = wp_p + 3 * 16384;                // 3 × 32768
    float* fbase = (float*)(wsn_p + 3 * 32768);     // 16B-aligned
    float* stats = fbase;                           // 256
    float* coef  = fbase + 256;                     // 256
    int* ibase = (int*)(fbase + 512);
    int* deg       = ibase;                         // 100000
    int* row_start = ibase + 100000;                // 100001
    int* cursor    = ibase + 200104;                // 100000
    int* esrc      = ibase + 300104;                // 1000000
    int* bsum      = ibase + 1300104;               // 128

    const int gGemm = (N_NODES + 127) / 128;        // 782
    const int gE    = (N_EDGES + 255) / 256;        // 3907
    const int gScan = (N_NODES + 1023) / 1024;      // 98
    const int gAgg  = (N_NODES + 3) / 4;            // 25000
    const long cvt4 = (long)(SZ / 4);               // 3.2M
    const long n2   = (long)(SZ / 2);               // 6.4M

    // ---- prep: bf16 node features + packed bf16 weights ----
    f32_to_bf16_kernel<<<(int)((cvt4 + 255) / 256), 256, 0, stream>>>(
        (const float4*)node_feat, (uint2*)Xbf, cvt4);
    for (int l = 0; l < 3; ++l)
        pack_weights3<<<192, 256, 0, stream>>>(wp[l], wsm[l], wn[l],
                                               wp_p + l * 16384, wsn_p + l * 32768);

    // ---- build CSR (graph static across layers) ----
    zero_kernel<<<98, 256, 0, stream>>>((float4*)deg, 25000);
    hist_kernel<<<gE, 256, 0, stream>>>(dst, deg);
    scan1_kernel<<<gScan, 256, 0, stream>>>(deg, bsum);
    scan2_kernel<<<1, 128, 0, stream>>>(bsum, gScan, row_start);
    scan3_kernel<<<gScan, 256, 0, stream>>>(deg, bsum, row_start, cursor);
    scatter_kernel<<<gE, 256, 0, stream>>>(src, dst, cursor, esrc);

    // ---- 3 SAGE layers ----
    const short* Xl[3]  = {Xbf, B0, B1};
    short* hpb[3]       = {B0, B1, B0};
    short* aggb[3]      = {B1, B2, B2};
    short* Yb[3]        = {B0, B1, B0};
    for (int l = 0; l < 3; ++l) {
        const short* X = Xl[l];
        gemm_mfma<4><<<gGemm, 256, 0, stream>>>(X, (const short*)nullptr,
            wp_p + l * 16384, bp[l], (unsigned short*)hpb[l], N_NODES, 1);
        aggregate_max_bf16<<<gAgg, 256, 0, stream>>>(
            (const unsigned int*)hpb[l], row_start, esrc, (unsigned int*)aggb[l]);
        const int act = (l == 0) ? 2 : 0;
        gemm_mfma<8><<<gGemm, 256, 0, stream>>>(X, aggb[l],
            wsn_p + l * 32768, bb[l], (unsigned short*)Yb[l], N_NODES, act);
        if (l == 1) {
            zero_kernel<<<1, 256, 0, stream>>>((float4*)stats, 64);
            bn_stats_kernel<<<(N_NODES + 511) / 512, 256, 0, stream>>>(
                (const unsigned short*)Yb[l], stats, N_NODES);
            bn_finalize_kernel<<<1, 128, 0, stream>>>(stats, gamma, beta, coef);
            bn_apply_bf16<<<(int)((n2 + 255) / 256), 256, 0, stream>>>(
                (unsigned int*)Yb[l], coef, n2);
        }
    }
    classifier_kernel<<<(N_NODES + 15) / 16, 256, 0, stream>>>(
        (const unsigned short*)B0, wc, bc, (float*)d_out, N_NODES);
}

// Round 6
// 639.261 us; speedup vs baseline: 4.1081x; 1.0236x over previous
//
#include <hip/hip_runtime.h>

// GraphSAGE-pool ×3 + BN + classifier, bf16 activations + MFMA GEMMs.
// R6 = R5 + (1) non-temporal stores in CSR scatter (kill 16x write
// amplification: 4B scatter writes dirtied 64B lines in 8 non-coherent XCD
// L2s -> 69.5 MB writeback for a 4 MB array); (2) aggregate edge loop
// unrolled x8 (deeper MLP toward L3-BW floor).

#define N_NODES 100000
#define N_EDGES 1000000
#define F 128
#define NEG_SLOPE 0.01f
#define BN_EPS 1e-5f

typedef __attribute__((ext_vector_type(8))) short bf16x8;
typedef __attribute__((ext_vector_type(4))) float f32x4;

typedef __attribute__((address_space(3))) unsigned int as3_uint;
typedef __attribute__((address_space(1))) const unsigned int as1_cuint;

__device__ __forceinline__ void gload16(const void* g, void* l) {
    __builtin_amdgcn_global_load_lds((as1_cuint*)g, (as3_uint*)l, 16, 0, 0);
}

__device__ __forceinline__ unsigned short f2bf(float f) {
    unsigned int u = __float_as_uint(f);
    u += 0x7fff + ((u >> 16) & 1);          // RNE
    return (unsigned short)(u >> 16);
}
__device__ __forceinline__ float bf2f(unsigned short h) {
    return __uint_as_float(((unsigned int)h) << 16);
}

// ---------------- zero fill ----------------
__global__ __launch_bounds__(256) void zero_kernel(float4* __restrict__ p, long n4) {
    long i = (long)blockIdx.x * 256 + threadIdx.x;
    if (i < n4) p[i] = make_float4(0.f, 0.f, 0.f, 0.f);
}

// ---------------- fp32 -> bf16 convert ----------------
__global__ __launch_bounds__(256) void f32_to_bf16_kernel(
    const float4* __restrict__ in, uint2* __restrict__ out, long n4)
{
    long i = (long)blockIdx.x * 256 + threadIdx.x;
    if (i >= n4) return;
    float4 v = in[i];
    uint2 o;
    o.x = (unsigned)f2bf(v.x) | ((unsigned)f2bf(v.y) << 16);
    o.y = (unsigned)f2bf(v.z) | ((unsigned)f2bf(v.w) << 16);
    out[i] = o;
}

// ---------------- weight pack: f32 [128][128] -> bf16 frag-order [16][128][8] ----------------
__global__ __launch_bounds__(256) void pack_weights3(
    const float* __restrict__ wp, const float* __restrict__ wss,
    const float* __restrict__ wn, short* __restrict__ wp_p, short* __restrict__ wsn_p)
{
    const int i = blockIdx.x * 256 + threadIdx.x;   // 0..49151
    if (i >= 3 * 16384) return;
    const int mat = i >> 14;
    const int idx = i & 16383;
    const int k = idx >> 7, n = idx & 127;
    const float* srcm = mat == 0 ? wp : (mat == 1 ? wss : wn);
    const int slot = ((k >> 3) * 128 + n) * 8 + (k & 7);
    if (mat == 0) wp_p[slot] = (short)f2bf(srcm[idx]);
    else wsn_p[(mat == 2 ? 16 * 128 * 8 : 0) + slot] = (short)f2bf(srcm[idx]);
}

// ---------------- MFMA GEMM, m97-style (unchanged from R5, verified) ----------------
template<int NKS>
__global__ __launch_bounds__(256) void gemm_mfma(
    const short* __restrict__ A1, const short* __restrict__ A2,
    const short* __restrict__ Bp, const float* __restrict__ bias,
    unsigned short* __restrict__ Cout, int n_rows, int act)
{
    constexpr int S = NKS / 2;                   // BK=64 steps
    __shared__ short tile[2 * 8192];             // 2 x (128 rows x 64 cols)
    __shared__ short epi[4 * 1280];              // per-wave 16 x 80

    const int tid = threadIdx.x;
    const int wave = tid >> 6;
    const int lane = tid & 63;
    const int m = lane & 15, q = lane >> 4;
    const int r0 = blockIdx.x * 128;
    const int rw = (wave >> 1) * 64;             // wave row-quadrant offset
    const int r0q = r0 + rw;
    const int c0 = (wave & 1) * 64;
    const int gchunk = (tid & 7) ^ ((tid >> 3) & 7);

    f32x4 acc[4][4];
#pragma unroll
    for (int i = 0; i < 4; ++i)
#pragma unroll
        for (int j = 0; j < 4; ++j)
#pragma unroll
            for (int r = 0; r < 4; ++r) acc[i][j][r] = 0.f;

    auto stage = [&](int s, int buf) {
        const short* Ap = (NKS == 8 && s >= 2) ? A2 : A1;
        const int kbase = (s & 1) * 64;          // shorts
#pragma unroll
        for (int p = 0; p < 4; ++p) {
            int row = r0 + (tid >> 3) + 32 * p;
            row = min(row, n_rows - 1);
            gload16(Ap + (size_t)row * F + kbase + gchunk * 8,
                    &tile[buf * 8192 + p * 2048 + tid * 8]);
        }
    };

    stage(0, 0);
    __syncthreads();

    for (int s = 0; s < S; ++s) {
        if (s + 1 < S) stage(s + 1, (s + 1) & 1);
        const short* tb = &tile[(s & 1) * 8192];
#pragma unroll
        for (int ks2 = 0; ks2 < 2; ++ks2) {
            const int ks32 = s * 2 + ks2;
            bf16x8 b[4], a[4];
#pragma unroll
            for (int ni = 0; ni < 4; ++ni)
                b[ni] = *(const bf16x8*)(Bp + ((size_t)(ks32 * 4 + q) * F + c0 + ni * 16 + m) * 8);
#pragma unroll
            for (int mi = 0; mi < 4; ++mi)
                a[mi] = *(const bf16x8*)(tb + (rw + mi * 16 + m) * 64 + (((ks2 * 4 + q) ^ (m & 7)) << 3));
#pragma unroll
            for (int mi = 0; mi < 4; ++mi)
#pragma unroll
                for (int ni = 0; ni < 4; ++ni)
                    acc[mi][ni] = __builtin_amdgcn_mfma_f32_16x16x32_bf16(a[mi], b[ni], acc[mi][ni], 0, 0, 0);
        }
        __syncthreads();
    }

    float bv[4];
#pragma unroll
    for (int ni = 0; ni < 4; ++ni) bv[ni] = bias[c0 + ni * 16 + m];

    short* ep = &epi[wave * 1280];
    const int colc_lo = m >> 3, cin = m & 7;
#pragma unroll
    for (int mi = 0; mi < 4; ++mi) {
#pragma unroll
        for (int ni = 0; ni < 4; ++ni) {
            const int colc = 2 * ni + colc_lo;
#pragma unroll
            for (int rg = 0; rg < 4; ++rg) {
                const int row16 = q * 4 + rg;
                float v = acc[mi][ni][rg] + bv[ni];
                if (act == 1) v = v > 0.f ? v : 0.f;
                else if (act == 2) v = v > 0.f ? v : v * NEG_SLOPE;
                ep[row16 * 80 + ((colc ^ (row16 & 7)) << 3) + cin] = (short)f2bf(v);
            }
        }
        __syncthreads();
#pragma unroll
        for (int p = 0; p < 2; ++p) {
            const int lrow = (lane >> 3) + 8 * p;
            bf16x8 vv = *(const bf16x8*)&ep[lrow * 80 + (((lane & 7) ^ (lrow & 7)) << 3)];
            const int grow = r0q + mi * 16 + lrow;
            if (grow < n_rows)
                *(bf16x8*)(Cout + (size_t)grow * F + c0 + ((lane & 7) << 3)) = vv;
        }
        __syncthreads();
    }
}

// ---------------- CSR build ----------------
__global__ __launch_bounds__(256) void hist_kernel(const int* __restrict__ dst, int* __restrict__ deg) {
    const int e = blockIdx.x * 256 + threadIdx.x;
    if (e < N_EDGES) atomicAdd(&deg[__builtin_nontemporal_load(&dst[e])], 1);
}

__global__ __launch_bounds__(256) void scan1_kernel(const int* __restrict__ deg, int* __restrict__ bsum) {
    __shared__ int sh[256];
    const int t = threadIdx.x;
    const int base = blockIdx.x * 1024 + t * 4;
    int s = 0;
#pragma unroll
    for (int j = 0; j < 4; ++j) s += (base + j < N_NODES) ? deg[base + j] : 0;
    sh[t] = s; __syncthreads();
    for (int off = 128; off; off >>= 1) {
        if (t < off) sh[t] += sh[t + off];
        __syncthreads();
    }
    if (t == 0) bsum[blockIdx.x] = sh[0];
}

__global__ __launch_bounds__(128) void scan2_kernel(int* __restrict__ bsum, int nb, int* __restrict__ row_start) {
    __shared__ int sh[128];
    const int t = threadIdx.x;
    sh[t] = (t < nb) ? bsum[t] : 0;
    __syncthreads();
    for (int off = 1; off < 128; off <<= 1) {
        int x = (t >= off) ? sh[t - off] : 0;
        __syncthreads();
        if (t >= off) sh[t] += x;
        __syncthreads();
    }
    if (t < nb) bsum[t] = t ? sh[t - 1] : 0;
    if (t == 0) row_start[N_NODES] = N_EDGES;
}

__global__ __launch_bounds__(256) void scan3_kernel(
    const int* __restrict__ deg, const int* __restrict__ boff,
    int* __restrict__ row_start, int* __restrict__ cursor)
{
    __shared__ int sh[256];
    const int t = threadIdx.x;
    const int base = blockIdx.x * 1024 + t * 4;
    int v[4]; int s = 0;
#pragma unroll
    for (int j = 0; j < 4; ++j) { v[j] = (base + j < N_NODES) ? deg[base + j] : 0; s += v[j]; }
    sh[t] = s; __syncthreads();
    for (int off = 1; off < 256; off <<= 1) {
        int x = (t >= off) ? sh[t - off] : 0;
        __syncthreads();
        if (t >= off) sh[t] += x;
        __syncthreads();
    }
    int excl = (t ? sh[t - 1] : 0) + boff[blockIdx.x];
#pragma unroll
    for (int j = 0; j < 4; ++j) {
        if (base + j < N_NODES) { row_start[base + j] = excl; cursor[base + j] = excl; }
        excl += v[j];
    }
}

// NT store on esrc: avoid dirty-line retention in per-XCD L2s (R5: 69.5 MB
// writeback for a 4 MB array). NT loads on the streaming src/dst reads.
__global__ __launch_bounds__(256) void scatter_kernel(
    const int* __restrict__ src, const int* __restrict__ dst,
    int* __restrict__ cursor, int* __restrict__ esrc)
{
    const int e = blockIdx.x * 256 + threadIdx.x;
    if (e < N_EDGES) {
        const int d = __builtin_nontemporal_load(&dst[e]);
        const int s = __builtin_nontemporal_load(&src[e]);
        const int pos = atomicAdd(&cursor[d], 1);
        __builtin_nontemporal_store(s, &esrc[pos]);
    }
}

// ---------------- aggregation: one wave per dst node, bf16 rows, 8-deep MLP ----------------
__global__ __launch_bounds__(256) void aggregate_max_bf16(
    const unsigned int* __restrict__ hp, const int* __restrict__ row_start,
    const int* __restrict__ esrc, unsigned int* __restrict__ agg)
{
    const int node = blockIdx.x * 4 + (threadIdx.x >> 6);
    if (node >= N_NODES) return;
    const int lane = threadIdx.x & 63;
    const int beg = row_start[node], end = row_start[node + 1];
    unsigned int m0 = 0, m1 = 0;
    int i = beg;
    for (; i + 7 < end; i += 8) {
        unsigned int v[8];
#pragma unroll
        for (int j = 0; j < 8; ++j) v[j] = hp[(size_t)esrc[i + j] * 64 + lane];
#pragma unroll
        for (int j = 0; j < 8; ++j) {
            m0 = max(m0, v[j] & 0xffffu);
            m1 = max(m1, v[j] >> 16);
        }
    }
    if (i + 3 < end) {
        unsigned int v[4];
#pragma unroll
        for (int j = 0; j < 4; ++j) v[j] = hp[(size_t)esrc[i + j] * 64 + lane];
#pragma unroll
        for (int j = 0; j < 4; ++j) {
            m0 = max(m0, v[j] & 0xffffu);
            m1 = max(m1, v[j] >> 16);
        }
        i += 4;
    }
    if (i + 1 < end) {
        const unsigned int a = hp[(size_t)esrc[i] * 64 + lane];
        const unsigned int b = hp[(size_t)esrc[i + 1] * 64 + lane];
        m0 = max(m0, max(a & 0xffffu, b & 0xffffu));
        m1 = max(m1, max(a >> 16, b >> 16));
        i += 2;
    }
    if (i < end) {
        const unsigned int a = hp[(size_t)esrc[i] * 64 + lane];
        m0 = max(m0, a & 0xffffu);
        m1 = max(m1, a >> 16);
    }
    agg[(size_t)node * 64 + lane] = m0 | (m1 << 16);
}

// ---------------- BN ----------------
__global__ __launch_bounds__(256) void bn_stats_kernel(
    const unsigned short* __restrict__ x, float* __restrict__ stats, int n)
{
    const int tid = threadIdx.x;
    const int c = tid & 127, half = tid >> 7;
    float s = 0.f, ss = 0.f;
    const int rend = min(n, (int)(blockIdx.x + 1) * 512);
    for (int r = blockIdx.x * 512 + half; r < rend; r += 2) {
        const float v = bf2f(x[(size_t)r * F + c]);
        s += v; ss = fmaf(v, v, ss);
    }
    __shared__ float sh[256];
    sh[tid] = s; __syncthreads();
    if (half == 0) atomicAdd(&stats[c], sh[c] + sh[c + 128]);
    __syncthreads();
    sh[tid] = ss; __syncthreads();
    if (half == 0) atomicAdd(&stats[128 + c], sh[c] + sh[c + 128]);
}

__global__ void bn_finalize_kernel(
    const float* __restrict__ stats, const float* __restrict__ gamma,
    const float* __restrict__ beta, float* __restrict__ coef)
{
    const int c = threadIdx.x;
    const float mean = stats[c] * (1.f / N_NODES);
    const float var = stats[128 + c] * (1.f / N_NODES) - mean * mean;
    const float scale = gamma[c] * rsqrtf(var + BN_EPS);
    coef[c] = scale;
    coef[128 + c] = fmaf(-mean, scale, beta[c]);
}

__global__ __launch_bounds__(256) void bn_apply_bf16(
    unsigned int* __restrict__ x, const float* __restrict__ coef, long n2)
{
    __shared__ float sc[128], sf[128];
    if (threadIdx.x < 128) {
        sc[threadIdx.x] = coef[threadIdx.x];
        sf[threadIdx.x] = coef[128 + threadIdx.x];
    }
    __syncthreads();
    const long i = (long)blockIdx.x * 256 + threadIdx.x;
    if (i >= n2) return;
    const unsigned int v = x[i];
    const int c0 = (int)(i & 63) * 2;
    float a = fmaf(bf2f((unsigned short)(v & 0xffffu)), sc[c0], sf[c0]);
    float b = fmaf(bf2f((unsigned short)(v >> 16)), sc[c0 + 1], sf[c0 + 1]);
    a = a > 0.f ? a : a * NEG_SLOPE;
    b = b > 0.f ? b : b * NEG_SLOPE;
    x[i] = (unsigned)f2bf(a) | ((unsigned)f2bf(b) << 16);
}

// ---------------- classifier ----------------
__global__ __launch_bounds__(256) void classifier_kernel(
    const unsigned short* __restrict__ X, const float* __restrict__ Wc,
    const float* __restrict__ bc, float* __restrict__ out, int n)
{
    __shared__ float Wl[2048];
    __shared__ float Xs[16 * 132];
    const int tid = threadIdx.x;
    for (int i = tid; i < 2048; i += 256) Wl[i] = Wc[i];
    const int r0 = blockIdx.x * 16;
    for (int i = tid; i < 2048; i += 256) {
        const int row = i >> 7, col = i & 127;
        const int gr = r0 + row;
        Xs[row * 132 + col] = (gr < n) ? bf2f(X[(size_t)gr * F + col]) : 0.f;
    }
    __syncthreads();
    const int rl = tid >> 4, c = tid & 15;
    const int r = r0 + rl;
    if (r >= n) return;
    float s = bc[c];
    const float* xr = &Xs[rl * 132];
#pragma unroll
    for (int k = 0; k < 128; ++k) s = fmaf(xr[k], Wl[k * 16 + c], s);
    out[(size_t)r * 16 + c] = s;
}

extern "C" void kernel_launch(void* const* d_in, const int* in_sizes, int n_in,
                              void* d_out, int out_size, void* d_ws, size_t ws_size,
                              hipStream_t stream) {
    const float* node_feat = (const float*)d_in[0];
    const int* src = (const int*)d_in[1];
    const int* dst = (const int*)d_in[2];
    const float* wp[3] = {(const float*)d_in[3],  (const float*)d_in[8],  (const float*)d_in[13]};
    const float* bp[3] = {(const float*)d_in[4],  (const float*)d_in[9],  (const float*)d_in[14]};
    const float* wsm[3] = {(const float*)d_in[5], (const float*)d_in[10], (const float*)d_in[15]};
    const float* wn[3] = {(const float*)d_in[6],  (const float*)d_in[11], (const float*)d_in[16]};
    const float* bb[3] = {(const float*)d_in[7],  (const float*)d_in[12], (const float*)d_in[17]};
    const float* gamma = (const float*)d_in[18];
    const float* beta  = (const float*)d_in[19];
    const float* wc    = (const float*)d_in[20];
    const float* bc    = (const float*)d_in[21];

    const size_t SZ = (size_t)N_NODES * F;          // 12.8M elements
    short* sbase = (short*)d_ws;
    short* B0  = sbase;
    short* B1  = sbase + SZ;
    short* B2  = sbase + 2 * SZ;
    short* Xbf = sbase + 3 * SZ;
    short* wp_p  = sbase + 4 * SZ;                  // 3 × 16384
    short* wsn_p = wp_p + 3 * 16384;                // 3 × 32768
    float* fbase = (float*)(wsn_p + 3 * 32768);     // 16B-aligned
    float* stats = fbase;                           // 256
    float* coef  = fbase + 256;                     // 256
    int* ibase = (int*)(fbase + 512);
    int* deg       = ibase;                         // 100000
    int* row_start = ibase + 100000;                // 100001
    int* cursor    = ibase + 200104;                // 100000
    int* esrc      = ibase + 300104;                // 1000000
    int* bsum      = ibase + 1300104;               // 128

    const int gGemm = (N_NODES + 127) / 128;        // 782
    const int gE    = (N_EDGES + 255) / 256;        // 3907
    const int gScan = (N_NODES + 1023) / 1024;      // 98
    const int gAgg  = (N_NODES + 3) / 4;            // 25000
    const long cvt4 = (long)(SZ / 4);               // 3.2M
    const long n2   = (long)(SZ / 2);               // 6.4M

    // ---- prep: bf16 node features + packed bf16 weights ----
    f32_to_bf16_kernel<<<(int)((cvt4 + 255) / 256), 256, 0, stream>>>(
        (const float4*)node_feat, (uint2*)Xbf, cvt4);
    for (int l = 0; l < 3; ++l)
        pack_weights3<<<192, 256, 0, stream>>>(wp[l], wsm[l], wn[l],
                                               wp_p + l * 16384, wsn_p + l * 32768);

    // ---- build CSR (graph static across layers) ----
    zero_kernel<<<98, 256, 0, stream>>>((float4*)deg, 25000);
    hist_kernel<<<gE, 256, 0, stream>>>(dst, deg);
    scan1_kernel<<<gScan, 256, 0, stream>>>(deg, bsum);
    scan2_kernel<<<1, 128, 0, stream>>>(bsum, gScan, row_start);
    scan3_kernel<<<gScan, 256, 0, stream>>>(deg, bsum, row_start, cursor);
    scatter_kernel<<<gE, 256, 0, stream>>>(src, dst, cursor, esrc);

    // ---- 3 SAGE layers ----
    const short* Xl[3]  = {Xbf, B0, B1};
    short* hpb[3]       = {B0, B1, B0};
    short* aggb[3]      = {B1, B2, B2};
    short* Yb[3]        = {B0, B1, B0};
    for (int l = 0; l < 3; ++l) {
        const short* X = Xl[l];
        gemm_mfma<4><<<gGemm, 256, 0, stream>>>(X, (const short*)nullptr,
            wp_p + l * 16384, bp[l], (unsigned short*)hpb[l], N_NODES, 1);
        aggregate_max_bf16<<<gAgg, 256, 0, stream>>>(
            (const unsigned int*)hpb[l], row_start, esrc, (unsigned int*)aggb[l]);
        const int act = (l == 0) ? 2 : 0;
        gemm_mfma<8><<<gGemm, 256, 0, stream>>>(X, aggb[l],
            wsn_p + l * 32768, bb[l], (unsigned short*)Yb[l], N_NODES, act);
        if (l == 1) {
            zero_kernel<<<1, 256, 0, stream>>>((float4*)stats, 64);
            bn_stats_kernel<<<(N_NODES + 511) / 512, 256, 0, stream>>>(
                (const unsigned short*)Yb[l], stats, N_NODES);
            bn_finalize_kernel<<<1, 128, 0, stream>>>(stats, gamma, beta, coef);
            bn_apply_bf16<<<(int)((n2 + 255) / 256), 256, 0, stream>>>(
                (unsigned int*)Yb[l], coef, n2);
        }
    }
    classifier_kernel<<<(N_NODES + 15) / 16, 256, 0, stream>>>(
        (const unsigned short*)B0, wc, bc, (float*)d_out, N_NODES);
}

// Round 7
// 603.787 us; speedup vs baseline: 4.3494x; 1.0588x over previous
//
#include <hip/hip_runtime.h>

// GraphSAGE-pool ×3 + BN + classifier, bf16 activations + MFMA GEMMs.
// R7 = R6 + XCD-partitioned CSR scatter: grid = 256 edge-chunks x 8
// dst-ranges with range == blockIdx&7 == XCD (round-robin dispatch, m09).
// Each esrc line is then written by exactly one XCD -> full-line writeback,
// killing the 18x write amplification NT stores couldn't fix (R6: 73 MB
// writeback for 4 MB payload; partial lines co-written by 8 L2s).

#define N_NODES 100000
#define N_EDGES 1000000
#define F 128
#define NEG_SLOPE 0.01f
#define BN_EPS 1e-5f

typedef __attribute__((ext_vector_type(8))) short bf16x8;
typedef __attribute__((ext_vector_type(4))) float f32x4;

typedef __attribute__((address_space(3))) unsigned int as3_uint;
typedef __attribute__((address_space(1))) const unsigned int as1_cuint;

__device__ __forceinline__ void gload16(const void* g, void* l) {
    __builtin_amdgcn_global_load_lds((as1_cuint*)g, (as3_uint*)l, 16, 0, 0);
}

__device__ __forceinline__ unsigned short f2bf(float f) {
    unsigned int u = __float_as_uint(f);
    u += 0x7fff + ((u >> 16) & 1);          // RNE
    return (unsigned short)(u >> 16);
}
__device__ __forceinline__ float bf2f(unsigned short h) {
    return __uint_as_float(((unsigned int)h) << 16);
}

// ---------------- zero fill ----------------
__global__ __launch_bounds__(256) void zero_kernel(float4* __restrict__ p, long n4) {
    long i = (long)blockIdx.x * 256 + threadIdx.x;
    if (i < n4) p[i] = make_float4(0.f, 0.f, 0.f, 0.f);
}

// ---------------- fp32 -> bf16 convert ----------------
__global__ __launch_bounds__(256) void f32_to_bf16_kernel(
    const float4* __restrict__ in, uint2* __restrict__ out, long n4)
{
    long i = (long)blockIdx.x * 256 + threadIdx.x;
    if (i >= n4) return;
    float4 v = in[i];
    uint2 o;
    o.x = (unsigned)f2bf(v.x) | ((unsigned)f2bf(v.y) << 16);
    o.y = (unsigned)f2bf(v.z) | ((unsigned)f2bf(v.w) << 16);
    out[i] = o;
}

// ---------------- weight pack: f32 [128][128] -> bf16 frag-order [16][128][8] ----------------
__global__ __launch_bounds__(256) void pack_weights3(
    const float* __restrict__ wp, const float* __restrict__ wss,
    const float* __restrict__ wn, short* __restrict__ wp_p, short* __restrict__ wsn_p)
{
    const int i = blockIdx.x * 256 + threadIdx.x;   // 0..49151
    if (i >= 3 * 16384) return;
    const int mat = i >> 14;
    const int idx = i & 16383;
    const int k = idx >> 7, n = idx & 127;
    const float* srcm = mat == 0 ? wp : (mat == 1 ? wss : wn);
    const int slot = ((k >> 3) * 128 + n) * 8 + (k & 7);
    if (mat == 0) wp_p[slot] = (short)f2bf(srcm[idx]);
    else wsn_p[(mat == 2 ? 16 * 128 * 8 : 0) + slot] = (short)f2bf(srcm[idx]);
}

// ---------------- MFMA GEMM, m97-style (verified R5) ----------------
template<int NKS>
__global__ __launch_bounds__(256) void gemm_mfma(
    const short* __restrict__ A1, const short* __restrict__ A2,
    const short* __restrict__ Bp, const float* __restrict__ bias,
    unsigned short* __restrict__ Cout, int n_rows, int act)
{
    constexpr int S = NKS / 2;                   // BK=64 steps
    __shared__ short tile[2 * 8192];             // 2 x (128 rows x 64 cols)
    __shared__ short epi[4 * 1280];              // per-wave 16 x 80

    const int tid = threadIdx.x;
    const int wave = tid >> 6;
    const int lane = tid & 63;
    const int m = lane & 15, q = lane >> 4;
    const int r0 = blockIdx.x * 128;
    const int rw = (wave >> 1) * 64;             // wave row-quadrant offset
    const int r0q = r0 + rw;
    const int c0 = (wave & 1) * 64;
    const int gchunk = (tid & 7) ^ ((tid >> 3) & 7);

    f32x4 acc[4][4];
#pragma unroll
    for (int i = 0; i < 4; ++i)
#pragma unroll
        for (int j = 0; j < 4; ++j)
#pragma unroll
            for (int r = 0; r < 4; ++r) acc[i][j][r] = 0.f;

    auto stage = [&](int s, int buf) {
        const short* Ap = (NKS == 8 && s >= 2) ? A2 : A1;
        const int kbase = (s & 1) * 64;          // shorts
#pragma unroll
        for (int p = 0; p < 4; ++p) {
            int row = r0 + (tid >> 3) + 32 * p;
            row = min(row, n_rows - 1);
            gload16(Ap + (size_t)row * F + kbase + gchunk * 8,
                    &tile[buf * 8192 + p * 2048 + tid * 8]);
        }
    };

    stage(0, 0);
    __syncthreads();

    for (int s = 0; s < S; ++s) {
        if (s + 1 < S) stage(s + 1, (s + 1) & 1);
        const short* tb = &tile[(s & 1) * 8192];
#pragma unroll
        for (int ks2 = 0; ks2 < 2; ++ks2) {
            const int ks32 = s * 2 + ks2;
            bf16x8 b[4], a[4];
#pragma unroll
            for (int ni = 0; ni < 4; ++ni)
                b[ni] = *(const bf16x8*)(Bp + ((size_t)(ks32 * 4 + q) * F + c0 + ni * 16 + m) * 8);
#pragma unroll
            for (int mi = 0; mi < 4; ++mi)
                a[mi] = *(const bf16x8*)(tb + (rw + mi * 16 + m) * 64 + (((ks2 * 4 + q) ^ (m & 7)) << 3));
#pragma unroll
            for (int mi = 0; mi < 4; ++mi)
#pragma unroll
                for (int ni = 0; ni < 4; ++ni)
                    acc[mi][ni] = __builtin_amdgcn_mfma_f32_16x16x32_bf16(a[mi], b[ni], acc[mi][ni], 0, 0, 0);
        }
        __syncthreads();
    }

    float bv[4];
#pragma unroll
    for (int ni = 0; ni < 4; ++ni) bv[ni] = bias[c0 + ni * 16 + m];

    short* ep = &epi[wave * 1280];
    const int colc_lo = m >> 3, cin = m & 7;
#pragma unroll
    for (int mi = 0; mi < 4; ++mi) {
#pragma unroll
        for (int ni = 0; ni < 4; ++ni) {
            const int colc = 2 * ni + colc_lo;
#pragma unroll
            for (int rg = 0; rg < 4; ++rg) {
                const int row16 = q * 4 + rg;
                float v = acc[mi][ni][rg] + bv[ni];
                if (act == 1) v = v > 0.f ? v : 0.f;
                else if (act == 2) v = v > 0.f ? v : v * NEG_SLOPE;
                ep[row16 * 80 + ((colc ^ (row16 & 7)) << 3) + cin] = (short)f2bf(v);
            }
        }
        __syncthreads();
#pragma unroll
        for (int p = 0; p < 2; ++p) {
            const int lrow = (lane >> 3) + 8 * p;
            bf16x8 vv = *(const bf16x8*)&ep[lrow * 80 + (((lane & 7) ^ (lrow & 7)) << 3)];
            const int grow = r0q + mi * 16 + lrow;
            if (grow < n_rows)
                *(bf16x8*)(Cout + (size_t)grow * F + c0 + ((lane & 7) << 3)) = vv;
        }
        __syncthreads();
    }
}

// ---------------- CSR build ----------------
__global__ __launch_bounds__(256) void hist_kernel(const int* __restrict__ dst, int* __restrict__ deg) {
    const int e = blockIdx.x * 256 + threadIdx.x;
    if (e < N_EDGES) atomicAdd(&deg[__builtin_nontemporal_load(&dst[e])], 1);
}

__global__ __launch_bounds__(256) void scan1_kernel(const int* __restrict__ deg, int* __restrict__ bsum) {
    __shared__ int sh[256];
    const int t = threadIdx.x;
    const int base = blockIdx.x * 1024 + t * 4;
    int s = 0;
#pragma unroll
    for (int j = 0; j < 4; ++j) s += (base + j < N_NODES) ? deg[base + j] : 0;
    sh[t] = s; __syncthreads();
    for (int off = 128; off; off >>= 1) {
        if (t < off) sh[t] += sh[t + off];
        __syncthreads();
    }
    if (t == 0) bsum[blockIdx.x] = sh[0];
}

__global__ __launch_bounds__(128) void scan2_kernel(int* __restrict__ bsum, int nb, int* __restrict__ row_start) {
    __shared__ int sh[128];
    const int t = threadIdx.x;
    sh[t] = (t < nb) ? bsum[t] : 0;
    __syncthreads();
    for (int off = 1; off < 128; off <<= 1) {
        int x = (t >= off) ? sh[t - off] : 0;
        __syncthreads();
        if (t >= off) sh[t] += x;
        __syncthreads();
    }
    if (t < nb) bsum[t] = t ? sh[t - 1] : 0;
    if (t == 0) row_start[N_NODES] = N_EDGES;
}

__global__ __launch_bounds__(256) void scan3_kernel(
    const int* __restrict__ deg, const int* __restrict__ boff,
    int* __restrict__ row_start, int* __restrict__ cursor)
{
    __shared__ int sh[256];
    const int t = threadIdx.x;
    const int base = blockIdx.x * 1024 + t * 4;
    int v[4]; int s = 0;
#pragma unroll
    for (int j = 0; j < 4; ++j) { v[j] = (base + j < N_NODES) ? deg[base + j] : 0; s += v[j]; }
    sh[t] = s; __syncthreads();
    for (int off = 1; off < 256; off <<= 1) {
        int x = (t >= off) ? sh[t - off] : 0;
        __syncthreads();
        if (t >= off) sh[t] += x;
        __syncthreads();
    }
    int excl = (t ? sh[t - 1] : 0) + boff[blockIdx.x];
#pragma unroll
    for (int j = 0; j < 4; ++j) {
        if (base + j < N_NODES) { row_start[base + j] = excl; cursor[base + j] = excl; }
        excl += v[j];
    }
}

// XCD-partitioned scatter: 2048 blocks = 256 edge-chunks x 8 dst-ranges.
// range = blockIdx&7 -> matches round-robin block->XCD dispatch, so each
// esrc line is written from exactly one XCD L2 (full-line writeback).
// Each edge is examined by 8 blocks, processed by 1 (dst reads L3-served).
#define NODES_PER_XCD 12500
__global__ __launch_bounds__(256) void scatter_xcd_kernel(
    const int* __restrict__ src, const int* __restrict__ dst,
    int* __restrict__ cursor, int* __restrict__ esrc)
{
    const int range = blockIdx.x & 7;
    const int chunk = blockIdx.x >> 3;            // 0..255
    const int lo = range * NODES_PER_XCD;
    const int e0 = chunk * 3907;
    const int e1 = min(e0 + 3907, N_EDGES);
    for (int e = e0 + threadIdx.x; e < e1; e += 256) {
        const int d = dst[e];
        const unsigned int rel = (unsigned int)(d - lo);
        if (rel < NODES_PER_XCD) {
            const int pos = atomicAdd(&cursor[d], 1);
            esrc[pos] = src[e];
        }
    }
}

// ---------------- aggregation: one wave per dst node, bf16 rows, 8-deep MLP ----------------
__global__ __launch_bounds__(256) void aggregate_max_bf16(
    const unsigned int* __restrict__ hp, const int* __restrict__ row_start,
    const int* __restrict__ esrc, unsigned int* __restrict__ agg)
{
    const int node = blockIdx.x * 4 + (threadIdx.x >> 6);
    if (node >= N_NODES) return;
    const int lane = threadIdx.x & 63;
    const int beg = row_start[node], end = row_start[node + 1];
    unsigned int m0 = 0, m1 = 0;
    int i = beg;
    for (; i + 7 < end; i += 8) {
        unsigned int v[8];
#pragma unroll
        for (int j = 0; j < 8; ++j) v[j] = hp[(size_t)esrc[i + j] * 64 + lane];
#pragma unroll
        for (int j = 0; j < 8; ++j) {
            m0 = max(m0, v[j] & 0xffffu);
            m1 = max(m1, v[j] >> 16);
        }
    }
    if (i + 3 < end) {
        unsigned int v[4];
#pragma unroll
        for (int j = 0; j < 4; ++j) v[j] = hp[(size_t)esrc[i + j] * 64 + lane];
#pragma unroll
        for (int j = 0; j < 4; ++j) {
            m0 = max(m0, v[j] & 0xffffu);
            m1 = max(m1, v[j] >> 16);
        }
        i += 4;
    }
    if (i + 1 < end) {
        const unsigned int a = hp[(size_t)esrc[i] * 64 + lane];
        const unsigned int b = hp[(size_t)esrc[i + 1] * 64 + lane];
        m0 = max(m0, max(a & 0xffffu, b & 0xffffu));
        m1 = max(m1, max(a >> 16, b >> 16));
        i += 2;
    }
    if (i < end) {
        const unsigned int a = hp[(size_t)esrc[i] * 64 + lane];
        m0 = max(m0, a & 0xffffu);
        m1 = max(m1, a >> 16);
    }
    agg[(size_t)node * 64 + lane] = m0 | (m1 << 16);
}

// ---------------- BN ----------------
__global__ __launch_bounds__(256) void bn_stats_kernel(
    const unsigned short* __restrict__ x, float* __restrict__ stats, int n)
{
    const int tid = threadIdx.x;
    const int c = tid & 127, half = tid >> 7;
    float s = 0.f, ss = 0.f;
    const int rend = min(n, (int)(blockIdx.x + 1) * 512);
    for (int r = blockIdx.x * 512 + half; r < rend; r += 2) {
        const float v = bf2f(x[(size_t)r * F + c]);
        s += v; ss = fmaf(v, v, ss);
    }
    __shared__ float sh[256];
    sh[tid] = s; __syncthreads();
    if (half == 0) atomicAdd(&stats[c], sh[c] + sh[c + 128]);
    __syncthreads();
    sh[tid] = ss; __syncthreads();
    if (half == 0) atomicAdd(&stats[128 + c], sh[c] + sh[c + 128]);
}

__global__ void bn_finalize_kernel(
    const float* __restrict__ stats, const float* __restrict__ gamma,
    const float* __restrict__ beta, float* __restrict__ coef)
{
    const int c = threadIdx.x;
    const float mean = stats[c] * (1.f / N_NODES);
    const float var = stats[128 + c] * (1.f / N_NODES) - mean * mean;
    const float scale = gamma[c] * rsqrtf(var + BN_EPS);
    coef[c] = scale;
    coef[128 + c] = fmaf(-mean, scale, beta[c]);
}

__global__ __launch_bounds__(256) void bn_apply_bf16(
    unsigned int* __restrict__ x, const float* __restrict__ coef, long n2)
{
    __shared__ float sc[128], sf[128];
    if (threadIdx.x < 128) {
        sc[threadIdx.x] = coef[threadIdx.x];
        sf[threadIdx.x] = coef[128 + threadIdx.x];
    }
    __syncthreads();
    const long i = (long)blockIdx.x * 256 + threadIdx.x;
    if (i >= n2) return;
    const unsigned int v = x[i];
    const int c0 = (int)(i & 63) * 2;
    float a = fmaf(bf2f((unsigned short)(v & 0xffffu)), sc[c0], sf[c0]);
    float b = fmaf(bf2f((unsigned short)(v >> 16)), sc[c0 + 1], sf[c0 + 1]);
    a = a > 0.f ? a : a * NEG_SLOPE;
    b = b > 0.f ? b : b * NEG_SLOPE;
    x[i] = (unsigned)f2bf(a) | ((unsigned)f2bf(b) << 16);
}

// ---------------- classifier ----------------
__global__ __launch_bounds__(256) void classifier_kernel(
    const unsigned short* __restrict__ X, const float* __restrict__ Wc,
    const float* __restrict__ bc, float* __restrict__ out, int n)
{
    __shared__ float Wl[2048];
    __shared__ float Xs[16 * 132];
    const int tid = threadIdx.x;
    for (int i = tid; i < 2048; i += 256) Wl[i] = Wc[i];
    const int r0 = blockIdx.x * 16;
    for (int i = tid; i < 2048; i += 256) {
        const int row = i >> 7, col = i & 127;
        const int gr = r0 + row;
        Xs[row * 132 + col] = (gr < n) ? bf2f(X[(size_t)gr * F + col]) : 0.f;
    }
    __syncthreads();
    const int rl = tid >> 4, c = tid & 15;
    const int r = r0 + rl;
    if (r >= n) return;
    float s = bc[c];
    const float* xr = &Xs[rl * 132];
#pragma unroll
    for (int k = 0; k < 128; ++k) s = fmaf(xr[k], Wl[k * 16 + c], s);
    out[(size_t)r * 16 + c] = s;
}

extern "C" void kernel_launch(void* const* d_in, const int* in_sizes, int n_in,
                              void* d_out, int out_size, void* d_ws, size_t ws_size,
                              hipStream_t stream) {
    const float* node_feat = (const float*)d_in[0];
    const int* src = (const int*)d_in[1];
    const int* dst = (const int*)d_in[2];
    const float* wp[3] = {(const float*)d_in[3],  (const float*)d_in[8],  (const float*)d_in[13]};
    const float* bp[3] = {(const float*)d_in[4],  (const float*)d_in[9],  (const float*)d_in[14]};
    const float* wsm[3] = {(const float*)d_in[5], (const float*)d_in[10], (const float*)d_in[15]};
    const float* wn[3] = {(const float*)d_in[6],  (const float*)d_in[11], (const float*)d_in[16]};
    const float* bb[3] = {(const float*)d_in[7],  (const float*)d_in[12], (const float*)d_in[17]};
    const float* gamma = (const float*)d_in[18];
    const float* beta  = (const float*)d_in[19];
    const float* wc    = (const float*)d_in[20];
    const float* bc    = (const float*)d_in[21];

    const size_t SZ = (size_t)N_NODES * F;          // 12.8M elements
    short* sbase = (short*)d_ws;
    short* B0  = sbase;
    short* B1  = sbase + SZ;
    short* B2  = sbase + 2 * SZ;
    short* Xbf = sbase + 3 * SZ;
    short* wp_p  = sbase + 4 * SZ;                  // 3 × 16384
    short* wsn_p = wp_p + 3 * 16384;                // 3 × 32768
    float* fbase = (float*)(wsn_p + 3 * 32768);     // 16B-aligned
    float* stats = fbase;                           // 256
    float* coef  = fbase + 256;                     // 256
    int* ibase = (int*)(fbase + 512);
    int* deg       = ibase;                         // 100000
    int* row_start = ibase + 100000;                // 100001
    int* cursor    = ibase + 200104;                // 100000
    int* esrc      = ibase + 300104;                // 1000000
    int* bsum      = ibase + 1300104;               // 128

    const int gGemm = (N_NODES + 127) / 128;        // 782
    const int gE    = (N_EDGES + 255) / 256;        // 3907
    const int gScan = (N_NODES + 1023) / 1024;      // 98
    const int gAgg  = (N_NODES + 3) / 4;            // 25000
    const long cvt4 = (long)(SZ / 4);               // 3.2M
    const long n2   = (long)(SZ / 2);               // 6.4M

    // ---- prep: bf16 node features + packed bf16 weights ----
    f32_to_bf16_kernel<<<(int)((cvt4 + 255) / 256), 256, 0, stream>>>(
        (const float4*)node_feat, (uint2*)Xbf, cvt4);
    for (int l = 0; l < 3; ++l)
        pack_weights3<<<192, 256, 0, stream>>>(wp[l], wsm[l], wn[l],
                                               wp_p + l * 16384, wsn_p + l * 32768);

    // ---- build CSR (graph static across layers) ----
    zero_kernel<<<98, 256, 0, stream>>>((float4*)deg, 25000);
    hist_kernel<<<gE, 256, 0, stream>>>(dst, deg);
    scan1_kernel<<<gScan, 256, 0, stream>>>(deg, bsum);
    scan2_kernel<<<1, 128, 0, stream>>>(bsum, gScan, row_start);
    scan3_kernel<<<gScan, 256, 0, stream>>>(deg, bsum, row_start, cursor);
    scatter_xcd_kernel<<<2048, 256, 0, stream>>>(src, dst, cursor, esrc);

    // ---- 3 SAGE layers ----
    const short* Xl[3]  = {Xbf, B0, B1};
    short* hpb[3]       = {B0, B1, B0};
    short* aggb[3]      = {B1, B2, B2};
    short* Yb[3]        = {B0, B1, B0};
    for (int l = 0; l < 3; ++l) {
        const short* X = Xl[l];
        gemm_mfma<4><<<gGemm, 256, 0, stream>>>(X, (const short*)nullptr,
            wp_p + l * 16384, bp[l], (unsigned short*)hpb[l], N_NODES, 1);
        aggregate_max_bf16<<<gAgg, 256, 0, stream>>>(
            (const unsigned int*)hpb[l], row_start, esrc, (unsigned int*)aggb[l]);
        const int act = (l == 0) ? 2 : 0;
        gemm_mfma<8><<<gGemm, 256, 0, stream>>>(X, aggb[l],
            wsn_p + l * 32768, bb[l], (unsigned short*)Yb[l], N_NODES, act);
        if (l == 1) {
            zero_kernel<<<1, 256, 0, stream>>>((float4*)stats, 64);
            bn_stats_kernel<<<(N_NODES + 511) / 512, 256, 0, stream>>>(
                (const unsigned short*)Yb[l], stats, N_NODES);
            bn_finalize_kernel<<<1, 128, 0, stream>>>(stats, gamma, beta, coef);
            bn_apply_bf16<<<(int)((n2 + 255) / 256), 256, 0, stream>>>(
                (unsigned int*)Yb[l], coef, n2);
        }
    }
    classifier_kernel<<<(N_NODES + 15) / 16, 256, 0, stream>>>(
        (const unsigned short*)B0, wc, bc, (float*)d_out, N_NODES);
}

// Round 8
// 557.359 us; speedup vs baseline: 4.7117x; 1.0833x over previous
//
#include <hip/hip_runtime.h>

// GraphSAGE-pool ×3 + BN + classifier, bf16 activations + MFMA GEMMs.
// R8 = R7 + bn_stats rewrite: was 196 blocks of scalar ushort loads
// (latency-bound, 67 us, 194 GB/s). Now 512 blocks, uint4 loads (4 full
// rows per wave-step, 1KB/wave-instr), register accumulate, shuffle+LDS
// reduce, 256 atomics/block.

#define N_NODES 100000
#define N_EDGES 1000000
#define F 128
#define NEG_SLOPE 0.01f
#define BN_EPS 1e-5f

typedef __attribute__((ext_vector_type(8))) short bf16x8;
typedef __attribute__((ext_vector_type(4))) float f32x4;

typedef __attribute__((address_space(3))) unsigned int as3_uint;
typedef __attribute__((address_space(1))) const unsigned int as1_cuint;

__device__ __forceinline__ void gload16(const void* g, void* l) {
    __builtin_amdgcn_global_load_lds((as1_cuint*)g, (as3_uint*)l, 16, 0, 0);
}

__device__ __forceinline__ unsigned short f2bf(float f) {
    unsigned int u = __float_as_uint(f);
    u += 0x7fff + ((u >> 16) & 1);          // RNE
    return (unsigned short)(u >> 16);
}
__device__ __forceinline__ float bf2f(unsigned short h) {
    return __uint_as_float(((unsigned int)h) << 16);
}

// ---------------- zero fill ----------------
__global__ __launch_bounds__(256) void zero_kernel(float4* __restrict__ p, long n4) {
    long i = (long)blockIdx.x * 256 + threadIdx.x;
    if (i < n4) p[i] = make_float4(0.f, 0.f, 0.f, 0.f);
}

// ---------------- fp32 -> bf16 convert ----------------
__global__ __launch_bounds__(256) void f32_to_bf16_kernel(
    const float4* __restrict__ in, uint2* __restrict__ out, long n4)
{
    long i = (long)blockIdx.x * 256 + threadIdx.x;
    if (i >= n4) return;
    float4 v = in[i];
    uint2 o;
    o.x = (unsigned)f2bf(v.x) | ((unsigned)f2bf(v.y) << 16);
    o.y = (unsigned)f2bf(v.z) | ((unsigned)f2bf(v.w) << 16);
    out[i] = o;
}

// ---------------- weight pack: f32 [128][128] -> bf16 frag-order [16][128][8] ----------------
__global__ __launch_bounds__(256) void pack_weights3(
    const float* __restrict__ wp, const float* __restrict__ wss,
    const float* __restrict__ wn, short* __restrict__ wp_p, short* __restrict__ wsn_p)
{
    const int i = blockIdx.x * 256 + threadIdx.x;   // 0..49151
    if (i >= 3 * 16384) return;
    const int mat = i >> 14;
    const int idx = i & 16383;
    const int k = idx >> 7, n = idx & 127;
    const float* srcm = mat == 0 ? wp : (mat == 1 ? wss : wn);
    const int slot = ((k >> 3) * 128 + n) * 8 + (k & 7);
    if (mat == 0) wp_p[slot] = (short)f2bf(srcm[idx]);
    else wsn_p[(mat == 2 ? 16 * 128 * 8 : 0) + slot] = (short)f2bf(srcm[idx]);
}

// ---------------- MFMA GEMM, m97-style (verified R5) ----------------
template<int NKS>
__global__ __launch_bounds__(256) void gemm_mfma(
    const short* __restrict__ A1, const short* __restrict__ A2,
    const short* __restrict__ Bp, const float* __restrict__ bias,
    unsigned short* __restrict__ Cout, int n_rows, int act)
{
    constexpr int S = NKS / 2;                   // BK=64 steps
    __shared__ short tile[2 * 8192];             // 2 x (128 rows x 64 cols)
    __shared__ short epi[4 * 1280];              // per-wave 16 x 80

    const int tid = threadIdx.x;
    const int wave = tid >> 6;
    const int lane = tid & 63;
    const int m = lane & 15, q = lane >> 4;
    const int r0 = blockIdx.x * 128;
    const int rw = (wave >> 1) * 64;             // wave row-quadrant offset
    const int r0q = r0 + rw;
    const int c0 = (wave & 1) * 64;
    const int gchunk = (tid & 7) ^ ((tid >> 3) & 7);

    f32x4 acc[4][4];
#pragma unroll
    for (int i = 0; i < 4; ++i)
#pragma unroll
        for (int j = 0; j < 4; ++j)
#pragma unroll
            for (int r = 0; r < 4; ++r) acc[i][j][r] = 0.f;

    auto stage = [&](int s, int buf) {
        const short* Ap = (NKS == 8 && s >= 2) ? A2 : A1;
        const int kbase = (s & 1) * 64;          // shorts
#pragma unroll
        for (int p = 0; p < 4; ++p) {
            int row = r0 + (tid >> 3) + 32 * p;
            row = min(row, n_rows - 1);
            gload16(Ap + (size_t)row * F + kbase + gchunk * 8,
                    &tile[buf * 8192 + p * 2048 + tid * 8]);
        }
    };

    stage(0, 0);
    __syncthreads();

    for (int s = 0; s < S; ++s) {
        if (s + 1 < S) stage(s + 1, (s + 1) & 1);
        const short* tb = &tile[(s & 1) * 8192];
#pragma unroll
        for (int ks2 = 0; ks2 < 2; ++ks2) {
            const int ks32 = s * 2 + ks2;
            bf16x8 b[4], a[4];
#pragma unroll
            for (int ni = 0; ni < 4; ++ni)
                b[ni] = *(const bf16x8*)(Bp + ((size_t)(ks32 * 4 + q) * F + c0 + ni * 16 + m) * 8);
#pragma unroll
            for (int mi = 0; mi < 4; ++mi)
                a[mi] = *(const bf16x8*)(tb + (rw + mi * 16 + m) * 64 + (((ks2 * 4 + q) ^ (m & 7)) << 3));
#pragma unroll
            for (int mi = 0; mi < 4; ++mi)
#pragma unroll
                for (int ni = 0; ni < 4; ++ni)
                    acc[mi][ni] = __builtin_amdgcn_mfma_f32_16x16x32_bf16(a[mi], b[ni], acc[mi][ni], 0, 0, 0);
        }
        __syncthreads();
    }

    float bv[4];
#pragma unroll
    for (int ni = 0; ni < 4; ++ni) bv[ni] = bias[c0 + ni * 16 + m];

    short* ep = &epi[wave * 1280];
    const int colc_lo = m >> 3, cin = m & 7;
#pragma unroll
    for (int mi = 0; mi < 4; ++mi) {
#pragma unroll
        for (int ni = 0; ni < 4; ++ni) {
            const int colc = 2 * ni + colc_lo;
#pragma unroll
            for (int rg = 0; rg < 4; ++rg) {
                const int row16 = q * 4 + rg;
                float v = acc[mi][ni][rg] + bv[ni];
                if (act == 1) v = v > 0.f ? v : 0.f;
                else if (act == 2) v = v > 0.f ? v : v * NEG_SLOPE;
                ep[row16 * 80 + ((colc ^ (row16 & 7)) << 3) + cin] = (short)f2bf(v);
            }
        }
        __syncthreads();
#pragma unroll
        for (int p = 0; p < 2; ++p) {
            const int lrow = (lane >> 3) + 8 * p;
            bf16x8 vv = *(const bf16x8*)&ep[lrow * 80 + (((lane & 7) ^ (lrow & 7)) << 3)];
            const int grow = r0q + mi * 16 + lrow;
            if (grow < n_rows)
                *(bf16x8*)(Cout + (size_t)grow * F + c0 + ((lane & 7) << 3)) = vv;
        }
        __syncthreads();
    }
}

// ---------------- CSR build ----------------
__global__ __launch_bounds__(256) void hist_kernel(const int* __restrict__ dst, int* __restrict__ deg) {
    const int e = blockIdx.x * 256 + threadIdx.x;
    if (e < N_EDGES) atomicAdd(&deg[__builtin_nontemporal_load(&dst[e])], 1);
}

__global__ __launch_bounds__(256) void scan1_kernel(const int* __restrict__ deg, int* __restrict__ bsum) {
    __shared__ int sh[256];
    const int t = threadIdx.x;
    const int base = blockIdx.x * 1024 + t * 4;
    int s = 0;
#pragma unroll
    for (int j = 0; j < 4; ++j) s += (base + j < N_NODES) ? deg[base + j] : 0;
    sh[t] = s; __syncthreads();
    for (int off = 128; off; off >>= 1) {
        if (t < off) sh[t] += sh[t + off];
        __syncthreads();
    }
    if (t == 0) bsum[blockIdx.x] = sh[0];
}

__global__ __launch_bounds__(128) void scan2_kernel(int* __restrict__ bsum, int nb, int* __restrict__ row_start) {
    __shared__ int sh[128];
    const int t = threadIdx.x;
    sh[t] = (t < nb) ? bsum[t] : 0;
    __syncthreads();
    for (int off = 1; off < 128; off <<= 1) {
        int x = (t >= off) ? sh[t - off] : 0;
        __syncthreads();
        if (t >= off) sh[t] += x;
        __syncthreads();
    }
    if (t < nb) bsum[t] = t ? sh[t - 1] : 0;
    if (t == 0) row_start[N_NODES] = N_EDGES;
}

__global__ __launch_bounds__(256) void scan3_kernel(
    const int* __restrict__ deg, const int* __restrict__ boff,
    int* __restrict__ row_start, int* __restrict__ cursor)
{
    __shared__ int sh[256];
    const int t = threadIdx.x;
    const int base = blockIdx.x * 1024 + t * 4;
    int v[4]; int s = 0;
#pragma unroll
    for (int j = 0; j < 4; ++j) { v[j] = (base + j < N_NODES) ? deg[base + j] : 0; s += v[j]; }
    sh[t] = s; __syncthreads();
    for (int off = 1; off < 256; off <<= 1) {
        int x = (t >= off) ? sh[t - off] : 0;
        __syncthreads();
        if (t >= off) sh[t] += x;
        __syncthreads();
    }
    int excl = (t ? sh[t - 1] : 0) + boff[blockIdx.x];
#pragma unroll
    for (int j = 0; j < 4; ++j) {
        if (base + j < N_NODES) { row_start[base + j] = excl; cursor[base + j] = excl; }
        excl += v[j];
    }
}

// XCD-partitioned scatter (verified R7): each esrc line written by one XCD.
#define NODES_PER_XCD 12500
__global__ __launch_bounds__(256) void scatter_xcd_kernel(
    const int* __restrict__ src, const int* __restrict__ dst,
    int* __restrict__ cursor, int* __restrict__ esrc)
{
    const int range = blockIdx.x & 7;
    const int chunk = blockIdx.x >> 3;            // 0..255
    const int lo = range * NODES_PER_XCD;
    const int e0 = chunk * 3907;
    const int e1 = min(e0 + 3907, N_EDGES);
    for (int e = e0 + threadIdx.x; e < e1; e += 256) {
        const int d = dst[e];
        const unsigned int rel = (unsigned int)(d - lo);
        if (rel < NODES_PER_XCD) {
            const int pos = atomicAdd(&cursor[d], 1);
            esrc[pos] = src[e];
        }
    }
}

// ---------------- aggregation: one wave per dst node, bf16 rows, 8-deep MLP ----------------
__global__ __launch_bounds__(256) void aggregate_max_bf16(
    const unsigned int* __restrict__ hp, const int* __restrict__ row_start,
    const int* __restrict__ esrc, unsigned int* __restrict__ agg)
{
    const int node = blockIdx.x * 4 + (threadIdx.x >> 6);
    if (node >= N_NODES) return;
    const int lane = threadIdx.x & 63;
    const int beg = row_start[node], end = row_start[node + 1];
    unsigned int m0 = 0, m1 = 0;
    int i = beg;
    for (; i + 7 < end; i += 8) {
        unsigned int v[8];
#pragma unroll
        for (int j = 0; j < 8; ++j) v[j] = hp[(size_t)esrc[i + j] * 64 + lane];
#pragma unroll
        for (int j = 0; j < 8; ++j) {
            m0 = max(m0, v[j] & 0xffffu);
            m1 = max(m1, v[j] >> 16);
        }
    }
    if (i + 3 < end) {
        unsigned int v[4];
#pragma unroll
        for (int j = 0; j < 4; ++j) v[j] = hp[(size_t)esrc[i + j] * 64 + lane];
#pragma unroll
        for (int j = 0; j < 4; ++j) {
            m0 = max(m0, v[j] & 0xffffu);
            m1 = max(m1, v[j] >> 16);
        }
        i += 4;
    }
    if (i + 1 < end) {
        const unsigned int a = hp[(size_t)esrc[i] * 64 + lane];
        const unsigned int b = hp[(size_t)esrc[i + 1] * 64 + lane];
        m0 = max(m0, max(a & 0xffffu, b & 0xffffu));
        m1 = max(m1, max(a >> 16, b >> 16));
        i += 2;
    }
    if (i < end) {
        const unsigned int a = hp[(size_t)esrc[i] * 64 + lane];
        m0 = max(m0, a & 0xffffu);
        m1 = max(m1, a >> 16);
    }
    agg[(size_t)node * 64 + lane] = m0 | (m1 << 16);
}

// ---------------- BN stats: 512 blocks, uint4 row loads, shuffle+LDS reduce ----------------
// Wave reads 4 full rows/step (lane = 16 colgroups x 4 rows); 8 cols/lane in
// registers; reduce lanes {l, l+16, l+32, l+48} via shfl, cross-wave via LDS,
// then 256 atomicAdds per block.
#define BN_ROWS_PER_BLOCK 196
__global__ __launch_bounds__(256) void bn_stats_kernel(
    const unsigned short* __restrict__ x, float* __restrict__ stats, int n)
{
    const int tid = threadIdx.x;
    const int wave = tid >> 6, lane = tid & 63;
    const int rgrp = lane >> 4;          // row within wave step
    const int c16 = lane & 15;           // col group (8 cols)
    const int rbase = blockIdx.x * BN_ROWS_PER_BLOCK;
    const int rend = min(rbase + BN_ROWS_PER_BLOCK, n);

    float s[8], ss[8];
#pragma unroll
    for (int j = 0; j < 8; ++j) { s[j] = 0.f; ss[j] = 0.f; }

    for (int r = rbase + wave * 4 + rgrp; r < rend; r += 16) {
        const uint4 v = *(const uint4*)(x + (size_t)r * F + c16 * 8);
        const unsigned int w[4] = {v.x, v.y, v.z, v.w};
#pragma unroll
        for (int u = 0; u < 4; ++u) {
            const float f0 = bf2f((unsigned short)(w[u] & 0xffffu));
            const float f1 = bf2f((unsigned short)(w[u] >> 16));
            s[2*u]   += f0; ss[2*u]   = fmaf(f0, f0, ss[2*u]);
            s[2*u+1] += f1; ss[2*u+1] = fmaf(f1, f1, ss[2*u+1]);
        }
    }
#pragma unroll
    for (int j = 0; j < 8; ++j) {
        s[j]  += __shfl_down(s[j], 32);  s[j]  += __shfl_down(s[j], 16);
        ss[j] += __shfl_down(ss[j], 32); ss[j] += __shfl_down(ss[j], 16);
    }
    __shared__ float sh[4][16][16];      // [wave][c16][j*2+stat]
    if (lane < 16) {
#pragma unroll
        for (int j = 0; j < 8; ++j) {
            sh[wave][c16][2*j]     = s[j];
            sh[wave][c16][2*j + 1] = ss[j];
        }
    }
    __syncthreads();
    // tid -> (c16 = tid>>4, idx = tid&15); idx = j*2+stat
    const float tot = sh[0][tid >> 4][tid & 15] + sh[1][tid >> 4][tid & 15]
                    + sh[2][tid >> 4][tid & 15] + sh[3][tid >> 4][tid & 15];
    const int col = (tid >> 4) * 8 + ((tid >> 1) & 7);
    atomicAdd(&stats[(tid & 1) * 128 + col], tot);
}

__global__ void bn_finalize_kernel(
    const float* __restrict__ stats, const float* __restrict__ gamma,
    const float* __restrict__ beta, float* __restrict__ coef)
{
    const int c = threadIdx.x;
    const float mean = stats[c] * (1.f / N_NODES);
    const float var = stats[128 + c] * (1.f / N_NODES) - mean * mean;
    const float scale = gamma[c] * rsqrtf(var + BN_EPS);
    coef[c] = scale;
    coef[128 + c] = fmaf(-mean, scale, beta[c]);
}

__global__ __launch_bounds__(256) void bn_apply_bf16(
    unsigned int* __restrict__ x, const float* __restrict__ coef, long n2)
{
    __shared__ float sc[128], sf[128];
    if (threadIdx.x < 128) {
        sc[threadIdx.x] = coef[threadIdx.x];
        sf[threadIdx.x] = coef[128 + threadIdx.x];
    }
    __syncthreads();
    const long i = (long)blockIdx.x * 256 + threadIdx.x;
    if (i >= n2) return;
    const unsigned int v = x[i];
    const int c0 = (int)(i & 63) * 2;
    float a = fmaf(bf2f((unsigned short)(v & 0xffffu)), sc[c0], sf[c0]);
    float b = fmaf(bf2f((unsigned short)(v >> 16)), sc[c0 + 1], sf[c0 + 1]);
    a = a > 0.f ? a : a * NEG_SLOPE;
    b = b > 0.f ? b : b * NEG_SLOPE;
    x[i] = (unsigned)f2bf(a) | ((unsigned)f2bf(b) << 16);
}

// ---------------- classifier ----------------
__global__ __launch_bounds__(256) void classifier_kernel(
    const unsigned short* __restrict__ X, const float* __restrict__ Wc,
    const float* __restrict__ bc, float* __restrict__ out, int n)
{
    __shared__ float Wl[2048];
    __shared__ float Xs[16 * 132];
    const int tid = threadIdx.x;
    for (int i = tid; i < 2048; i += 256) Wl[i] = Wc[i];
    const int r0 = blockIdx.x * 16;
    for (int i = tid; i < 2048; i += 256) {
        const int row = i >> 7, col = i & 127;
        const int gr = r0 + row;
        Xs[row * 132 + col] = (gr < n) ? bf2f(X[(size_t)gr * F + col]) : 0.f;
    }
    __syncthreads();
    const int rl = tid >> 4, c = tid & 15;
    const int r = r0 + rl;
    if (r >= n) return;
    float s = bc[c];
    const float* xr = &Xs[rl * 132];
#pragma unroll
    for (int k = 0; k < 128; ++k) s = fmaf(xr[k], Wl[k * 16 + c], s);
    out[(size_t)r * 16 + c] = s;
}

extern "C" void kernel_launch(void* const* d_in, const int* in_sizes, int n_in,
                              void* d_out, int out_size, void* d_ws, size_t ws_size,
                              hipStream_t stream) {
    const float* node_feat = (const float*)d_in[0];
    const int* src = (const int*)d_in[1];
    const int* dst = (const int*)d_in[2];
    const float* wp[3] = {(const float*)d_in[3],  (const float*)d_in[8],  (const float*)d_in[13]};
    const float* bp[3] = {(const float*)d_in[4],  (const float*)d_in[9],  (const float*)d_in[14]};
    const float* wsm[3] = {(const float*)d_in[5], (const float*)d_in[10], (const float*)d_in[15]};
    const float* wn[3] = {(const float*)d_in[6],  (const float*)d_in[11], (const float*)d_in[16]};
    const float* bb[3] = {(const float*)d_in[7],  (const float*)d_in[12], (const float*)d_in[17]};
    const float* gamma = (const float*)d_in[18];
    const float* beta  = (const float*)d_in[19];
    const float* wc    = (const float*)d_in[20];
    const float* bc    = (const float*)d_in[21];

    const size_t SZ = (size_t)N_NODES * F;          // 12.8M elements
    short* sbase = (short*)d_ws;
    short* B0  = sbase;
    short* B1  = sbase + SZ;
    short* B2  = sbase + 2 * SZ;
    short* Xbf = sbase + 3 * SZ;
    short* wp_p  = sbase + 4 * SZ;                  // 3 × 16384
    short* wsn_p = wp_p + 3 * 16384;                // 3 × 32768
    float* fbase = (float*)(wsn_p + 3 * 32768);     // 16B-aligned
    float* stats = fbase;                           // 256
    float* coef  = fbase + 256;                     // 256
    int* ibase = (int*)(fbase + 512);
    int* deg       = ibase;                         // 100000
    int* row_start = ibase + 100000;                // 100001
    int* cursor    = ibase + 200104;                // 100000
    int* esrc      = ibase + 300104;                // 1000000
    int* bsum      = ibase + 1300104;               // 128

    const int gGemm = (N_NODES + 127) / 128;        // 782
    const int gE    = (N_EDGES + 255) / 256;        // 3907
    const int gScan = (N_NODES + 1023) / 1024;      // 98
    const int gAgg  = (N_NODES + 3) / 4;            // 25000
    const long cvt4 = (long)(SZ / 4);               // 3.2M
    const long n2   = (long)(SZ / 2);               // 6.4M

    // ---- prep: bf16 node features + packed bf16 weights ----
    f32_to_bf16_kernel<<<(int)((cvt4 + 255) / 256), 256, 0, stream>>>(
        (const float4*)node_feat, (uint2*)Xbf, cvt4);
    for (int l = 0; l < 3; ++l)
        pack_weights3<<<192, 256, 0, stream>>>(wp[l], wsm[l], wn[l],
                                               wp_p + l * 16384, wsn_p + l * 32768);

    // ---- build CSR (graph static across layers) ----
    zero_kernel<<<98, 256, 0, stream>>>((float4*)deg, 25000);
    hist_kernel<<<gE, 256, 0, stream>>>(dst, deg);
    scan1_kernel<<<gScan, 256, 0, stream>>>(deg, bsum);
    scan2_kernel<<<1, 128, 0, stream>>>(bsum, gScan, row_start);
    scan3_kernel<<<gScan, 256, 0, stream>>>(deg, bsum, row_start, cursor);
    scatter_xcd_kernel<<<2048, 256, 0, stream>>>(src, dst, cursor, esrc);

    // ---- 3 SAGE layers ----
    const short* Xl[3]  = {Xbf, B0, B1};
    short* hpb[3]       = {B0, B1, B0};
    short* aggb[3]      = {B1, B2, B2};
    short* Yb[3]        = {B0, B1, B0};
    for (int l = 0; l < 3; ++l) {
        const short* X = Xl[l];
        gemm_mfma<4><<<gGemm, 256, 0, stream>>>(X, (const short*)nullptr,
            wp_p + l * 16384, bp[l], (unsigned short*)hpb[l], N_NODES, 1);
        aggregate_max_bf16<<<gAgg, 256, 0, stream>>>(
            (const unsigned int*)hpb[l], row_start, esrc, (unsigned int*)aggb[l]);
        const int act = (l == 0) ? 2 : 0;
        gemm_mfma<8><<<gGemm, 256, 0, stream>>>(X, aggb[l],
            wsn_p + l * 32768, bb[l], (unsigned short*)Yb[l], N_NODES, act);
        if (l == 1) {
            zero_kernel<<<1, 256, 0, stream>>>((float4*)stats, 64);
            bn_stats_kernel<<<512, 256, 0, stream>>>(
                (const unsigned short*)Yb[l], stats, N_NODES);
            bn_finalize_kernel<<<1, 128, 0, stream>>>(stats, gamma, beta, coef);
            bn_apply_bf16<<<(int)((n2 + 255) / 256), 256, 0, stream>>>(
                (unsigned int*)Yb[l], coef, n2);
        }
    }
    classifier_kernel<<<(N_NODES + 15) / 16, 256, 0, stream>>>(
        (const unsigned short*)B0, wc, bc, (float*)d_out, N_NODES);
}